// Round 9
// baseline (1696.052 us; speedup 1.0000x reference)
//
#include <hip/hip_runtime.h>
#include <hip/hip_bf16.h>
#include <math.h>

// ---------------- problem constants ----------------
#define B_   8
#define T_   12
#define N_   325
#define C_   64
#define NT   3900     // N_*T_
#define LSP  328      // padded row stride of transposed sp matrix

__device__ __forceinline__ float sigm(float x) { return 1.f / (1.f + expf(-x)); }

// 512-thread (8-wave) multi-value reduction; ONE barrier (caller ping-pongs redb)
__device__ __forceinline__ void redN(float* v, int nv, float (*redb)[4], int tid) {
#pragma unroll
  for (int off = 1; off < 64; off <<= 1) {
    for (int i = 0; i < nv; i++) v[i] += __shfl_xor(v[i], off, 64);
  }
  if ((tid & 63) == 0) {
    for (int i = 0; i < nv; i++) redb[tid >> 6][i] = v[i];
  }
  __syncthreads();
  for (int i = 0; i < nv; i++) {
    float s = 0.f;
#pragma unroll
    for (int w = 0; w < 8; w++) s += redb[w][i];
    v[i] = s;
  }
}

// ---------------- sentinel (ws too small diagnostic) ----------------
__global__ __launch_bounds__(256) void k_sentinel(float* out, int n) {
  int i = blockIdx.x * 256 + threadIdx.x;
  if (i < n) out[i] = 7.0f;
}

// ---------------- k0: transpose sp (padded) ----------------
__global__ __launch_bounds__(256) void k0_convert(const float* __restrict__ sp,
                                                  float* __restrict__ LsT) {
  int idx = blockIdx.x * 256 + threadIdx.x;
  if (idx < N_ * LSP) {
    int m = idx / LSP, n = idx - m * LSP;
    LsT[idx] = (n < N_) ? sp[n * N_ + m] : 0.f;   // LsT[m][n] = Ls[n][m]
  }
}

// ---------------- k1: embeddings + theta coefficients ----------------
__global__ __launch_bounds__(256) void k1_embed(
    const int* __restrict__ TE, const float* __restrict__ SE,
    const float* __restrict__ w1, const float* __restrict__ b1,
    const float* __restrict__ w2, const float* __restrict__ b2,
    const float* __restrict__ sw1, const float* __restrict__ sb1,
    const float* __restrict__ sw2, const float* __restrict__ sb2,
    const float* __restrict__ t1w, const float* __restrict__ t1b,
    const float* __restrict__ t2w, const float* __restrict__ t2b,
    float* __restrict__ coef) {
  __shared__ float te2[8][10][12];
  __shared__ float ste[8][5][10];
  __shared__ float se1[5][10];
  __shared__ float se2[5][10];
  __shared__ float th[8][6][10];
  __shared__ int te64;
  const int tid = threadIdx.x;
  if (tid == 0) {
    int nz = 0;
    for (int k2 = 0; k2 < 96; k2++) nz += (TE[2 * k2 + 1] != 0) ? 1 : 0;
    te64 = (nz == 0) ? 1 : 0;
  }
  __syncthreads();
  for (int idx = tid; idx < 960; idx += 256) {
    int t = idx % 12, o = (idx / 12) % 10, b = idx / 120;
    int q = (b * 12 + t) * 2;
    int d = (te64 ? TE[2 * q] : TE[q]) % 7;
    int h = (te64 ? TE[2 * q + 2] : TE[q + 1]) % 288;
    float v = w1[o * 295 + d] + w1[o * 295 + 7 + h] + b1[o];
    te2[b][o][t] = fmaxf(v, 0.f);
  }
  __syncthreads();
  for (int idx = tid; idx < 400; idx += 256) {
    int s = idx % 10, o = (idx / 10) % 5, b = idx / 50;
    float a = b2[o];
    for (int t = 0; t < 12; t++) a += te2[b][s][t] * w2[o * 12 + t];
    ste[b][o][s] = fmaxf(a, 0.f);
  }
  if (tid < 50) {
    int o = tid / 10, j = tid % 10;
    float a = sb1[o];
    for (int n = 0; n < N_; n++) a += sw1[o * N_ + n] * SE[n * 10 + j];
    se1[o][j] = fmaxf(a, 0.f);
  }
  __syncthreads();
  if (tid < 50) {
    int t = tid / 10, s = tid % 10;
    float a = sb2[s];
    for (int j = 0; j < 10; j++) a += sw2[s * 10 + j] * se1[t][j];
    se2[t][s] = fmaxf(a, 0.f);
  }
  __syncthreads();
  for (int idx = tid; idx < 400; idx += 256) {
    int s = idx % 10, o = (idx / 10) % 5, b = idx / 50;
    ste[b][o][s] = fmaxf(se2[o][s] + ste[b][o][s], 0.f);
  }
  __syncthreads();
  for (int l = 0; l < 2; l++) {
    for (int idx = tid; idx < 480; idx += 256) {
      int s = idx % 10, q = (idx / 10) % 6, b = idx / 60;
      float a = t1b[l * 6 + q];
      for (int t = 0; t < 5; t++) a += ste[b][t][s] * t1w[(l * 6 + q) * 5 + t];
      th[b][q][s] = a;
    }
    __syncthreads();
    for (int idx = tid; idx < 528; idx += 256) {
      int q = idx % 6, p = (idx / 6) % 11, b = idx / 66;
      float a = t2b[l * 11 + p];
      for (int s = 0; s < 10; s++) a += th[b][q][s] * t2w[(l * 11 + p) * 10 + s];
      coef[(l * 8 + b) * 66 + q * 11 + p] = fmaxf(a, 0.f);
    }
    __syncthreads();
  }
}

// ---------------- k2: start 1x1 conv ----------------
__global__ __launch_bounds__(256) void k2_start(const float* __restrict__ src,
                                                const float* __restrict__ w,
                                                const float* __restrict__ bia,
                                                float* __restrict__ x) {
  int idx = blockIdx.x * 256 + threadIdx.x;
  if (idx >= B_ * C_ * NT) return;
  int pos = idx % NT, r = idx / NT, c = r & 63, b = r >> 6;
  int n = pos / 12, t = pos - 12 * n;
  float s = src[(b * 12 + t) * N_ + n];
  x[idx] = s * w[c] + bia[c];
}

// ---------------- k3: fused basis recursion + x_st accumulation ----------------
// Spatial steps: 4-row x 4-col register tiles (82x3 = 246 threads) so each
// ds_read_b128 of M[mm, t0:t0+4] feeds 16 FMA (was 8) -> LDS pipe halved.
// Temporal chain: row-local in registers (tridiagonal tp), as in R7.
__global__ __launch_bounds__(512, 4) void k3_basis(
    const float* __restrict__ x, const float* __restrict__ LsT,
    const float* __restrict__ tp, const float* __restrict__ coef,
    float* __restrict__ xst) {
  __shared__ float sb[2][3904];
  __shared__ float sred[2][8][4];
  const int tid = threadIdx.x;
  const int bc = blockIdx.x;
  const float* cf = coef + (bc >> 6) * 66;
  const float* xs = x + (size_t)bc * NT;
  float* xo = xst + (size_t)bc * NT;

  // spatial tiling: 82 row-quads x 3 t-quads = 246 threads
  const int pr = tid / 3, tb = tid - 3 * pr;
  const int n0 = 4 * pr, t0 = 4 * tb;
  const bool actS = (tid < 246);
  const int e0 = n0 * 12 + t0;

  // temporal layout: one row per thread (325 active)
  const bool actT = (tid < N_);
  const int rowOff = tid * 12;

  float w[11];
#pragma unroll
  for (int k = 0; k < 11; k++) w[k] = tp[k * 12 + k + 1];

  float last[12], sec[12], acc[12], rr[12];

  int p = 0, m = 0, spc = 0;

  // ---- m00 = unit(residual slice) (temporal layout) ----
  {
    float np = 0.f;
#pragma unroll
    for (int u = 0; u < 12; u++) rr[u] = 0.f;
    if (actT) {
      const float4 a = *(const float4*)(xs + rowOff);
      const float4 b4 = *(const float4*)(xs + rowOff + 4);
      const float4 c4 = *(const float4*)(xs + rowOff + 8);
      rr[0] = a.x; rr[1] = a.y; rr[2] = a.z; rr[3] = a.w;
      rr[4] = b4.x; rr[5] = b4.y; rr[6] = b4.z; rr[7] = b4.w;
      rr[8] = c4.x; rr[9] = c4.y; rr[10] = c4.z; rr[11] = c4.w;
#pragma unroll
      for (int u = 0; u < 12; u++) np += rr[u] * rr[u];
    }
    p ^= 1; redN(&np, 1, sred[p], tid);
    const float inv = 1.f / fmaxf(sqrtf(np), 1e-8f);
    const float c0 = cf[m]; m++;
#pragma unroll
    for (int u = 0; u < 12; u++) {
      last[u] = rr[u] * inv;
      acc[u] = c0 * last[u];
      sec[u] = 0.f;
    }
    if (actT) {
      float4 wv;
      wv.x = last[0]; wv.y = last[1]; wv.z = last[2]; wv.w = last[3];
      *(float4*)&sb[0][rowOff] = wv;
      wv.x = last[4]; wv.y = last[5]; wv.z = last[6]; wv.w = last[7];
      *(float4*)&sb[0][rowOff + 4] = wv;
      wv.x = last[8]; wv.y = last[9]; wv.z = last[10]; wv.w = last[11];
      *(float4*)&sb[0][rowOff + 8] = wv;
    }
    __syncthreads();
  }

  for (int i = 0; i <= 10; i++) {
    if (i > 0) {
      // ---------- spatial step: last_s = sb[spc], sec_s = sb[sps] ----------
      const int sps = 1 - spc;
      const bool hasSec = (i >= 2);
      float v3[3] = {0.f, 0.f, 0.f};
      float rt[4][4], lt4[4][4], st4[4][4];
#pragma unroll
      for (int ii = 0; ii < 4; ii++)
#pragma unroll
        for (int j = 0; j < 4; j++) { rt[ii][j] = 0.f; lt4[ii][j] = 0.f; st4[ii][j] = 0.f; }
      if (actS) {
        const float* lpc = LsT + n0;
        const float* sc = &sb[spc][t0];
#pragma unroll 4
        for (int mm = 0; mm < N_; mm++) {
          const float4 a = *(const float4*)(lpc + mm * LSP);   // pad cols -> 0
          const float4 mr = *(const float4*)(sc + mm * 12);
          rt[0][0] += a.x * mr.x; rt[0][1] += a.x * mr.y; rt[0][2] += a.x * mr.z; rt[0][3] += a.x * mr.w;
          rt[1][0] += a.y * mr.x; rt[1][1] += a.y * mr.y; rt[1][2] += a.y * mr.z; rt[1][3] += a.y * mr.w;
          rt[2][0] += a.z * mr.x; rt[2][1] += a.z * mr.y; rt[2][2] += a.z * mr.z; rt[2][3] += a.z * mr.w;
          rt[3][0] += a.w * mr.x; rt[3][1] += a.w * mr.y; rt[3][2] += a.w * mr.z; rt[3][3] += a.w * mr.w;
        }
#pragma unroll
        for (int ii = 0; ii < 4; ii++)
          if (n0 + ii < N_) {
            const float4 q = *(const float4*)&sb[spc][e0 + ii * 12];
            lt4[ii][0] = q.x; lt4[ii][1] = q.y; lt4[ii][2] = q.z; lt4[ii][3] = q.w;
#pragma unroll
            for (int j = 0; j < 4; j++) v3[0] += rt[ii][j] * lt4[ii][j];
          }
        if (hasSec) {
#pragma unroll
          for (int ii = 0; ii < 4; ii++)
            if (n0 + ii < N_) {
              const float4 q = *(const float4*)&sb[sps][e0 + ii * 12];
              st4[ii][0] = q.x; st4[ii][1] = q.y; st4[ii][2] = q.z; st4[ii][3] = q.w;
#pragma unroll
              for (int j = 0; j < 4; j++) {
                v3[1] += rt[ii][j] * st4[ii][j];
                v3[2] += lt4[ii][j] * st4[ii][j];
              }
            }
        }
      }
      p ^= 1;
      if (hasSec) redN(v3, 3, sred[p], tid); else redN(v3, 1, sred[p], tid);
      const float d1 = v3[0];
      const float d2 = hasSec ? (v3[1] - d1 * v3[2]) : 0.f;
      float np = 0.f;
      if (actS) {
#pragma unroll
        for (int ii = 0; ii < 4; ii++)
#pragma unroll
          for (int j = 0; j < 4; j++) {
            rt[ii][j] -= d1 * lt4[ii][j] + d2 * st4[ii][j];
            np += rt[ii][j] * rt[ii][j];   // invalid rows: rt==0 (LsT pad)
          }
      }
      p ^= 1; redN(&np, 1, sred[p], tid);
      const float inv = 1.f / fmaxf(sqrtf(np), 1e-8f);
      const float cs = cf[m]; m++;
      if (actS) {
#pragma unroll
        for (int ii = 0; ii < 4; ii++)
          if (n0 + ii < N_) {
            float4 wv;
            wv.x = rt[ii][0] * inv; wv.y = rt[ii][1] * inv;
            wv.z = rt[ii][2] * inv; wv.w = rt[ii][3] * inv;
            *(float4*)&sb[sps][e0 + ii * 12] = wv;
          }
      }
      spc = sps;
      __syncthreads();
      // temporal-layout init: load new M_i0 row; acc += c*row; sec <- 0
      if (actT) {
        const float4 a = *(const float4*)&sb[spc][rowOff];
        const float4 b4 = *(const float4*)&sb[spc][rowOff + 4];
        const float4 c4 = *(const float4*)&sb[spc][rowOff + 8];
        last[0] = a.x; last[1] = a.y; last[2] = a.z; last[3] = a.w;
        last[4] = b4.x; last[5] = b4.y; last[6] = b4.z; last[7] = b4.w;
        last[8] = c4.x; last[9] = c4.y; last[10] = c4.z; last[11] = c4.w;
#pragma unroll
        for (int u = 0; u < 12; u++) {
          acc[u] += cs * last[u];
          sec[u] = 0.f;
        }
      }
    }
    // ---------- temporal chain (5 steps), fully register-resident ----------
    for (int j5 = 0; j5 < 5; j5++) {
      float v3[3] = {0.f, 0.f, 0.f};
      if (actT) {
#pragma unroll
        for (int u = 0; u < 12; u++) {
          float r = 0.f;
          if (u > 0) r += last[u - 1] * w[u - 1];
          if (u < 11) r += last[u + 1] * w[u];
          rr[u] = r;
          v3[0] += r * last[u];
          v3[1] += r * sec[u];
          v3[2] += last[u] * sec[u];
        }
      }
      p ^= 1; redN(v3, 3, sred[p], tid);
      const float d1 = v3[0];
      const float d2 = v3[1] - d1 * v3[2];
      float np = 0.f;
      if (actT) {
#pragma unroll
        for (int u = 0; u < 12; u++) {
          rr[u] -= d1 * last[u] + d2 * sec[u];
          np += rr[u] * rr[u];
        }
      }
      p ^= 1; redN(&np, 1, sred[p], tid);
      const float inv = 1.f / fmaxf(sqrtf(np), 1e-8f);
      const float c = cf[m]; m++;
      if (actT) {
#pragma unroll
        for (int u = 0; u < 12; u++) {
          const float v = rr[u] * inv;
          sec[u] = last[u];
          last[u] = v;
          acc[u] += c * v;
        }
      }
    }
  }
  if (actT) {
    float4 wv;
    wv.x = acc[0]; wv.y = acc[1]; wv.z = acc[2]; wv.w = acc[3];
    *(float4*)(xo + rowOff) = wv;
    wv.x = acc[4]; wv.y = acc[5]; wv.z = acc[6]; wv.w = acc[7];
    *(float4*)(xo + rowOff + 4) = wv;
    wv.x = acc[8]; wv.y = acc[9]; wv.z = acc[10]; wv.w = acc[11];
    *(float4*)(xo + rowOff + 8) = wv;
  }
}

// ---------------- k45: fused layer body, one block per (b,n) ----------------
// Register-tiled: 4 outputs per thread for hidden/g1/fusion (each LDS
// activation read feeds 4-8 accumulators), 2 for g2/g3.
__global__ __launch_bounds__(256) void k45_layer(
    float* __restrict__ x, const float* __restrict__ xst,
    const float* __restrict__ stw, const float* __restrict__ stb,
    const float* __restrict__ stg, const float* __restrict__ stbb,
    const float* __restrict__ stm, const float* __restrict__ stv,
    const float* __restrict__ p1w, const float* __restrict__ p1b,
    const float* __restrict__ p2w, const float* __restrict__ p2b,
    const float* __restrict__ p3w, const float* __restrict__ p3b,
    const float* __restrict__ pcw, const float* __restrict__ pcb,
    const float* __restrict__ pbg, const float* __restrict__ pbb,
    const float* __restrict__ pbm, const float* __restrict__ pbv,
    const float* __restrict__ bng, const float* __restrict__ bnb,
    const float* __restrict__ bnm, const float* __restrict__ bnv,
    const float* __restrict__ skw, const float* __restrict__ skb,
    float* __restrict__ skipb, int accum) {
  __shared__ float xr[64][12];
  __shared__ float xq[64][12];
  __shared__ float hd[64][12];
  __shared__ float g1s[64][12];
  __shared__ float g2s[64][4];
  __shared__ float g3s[64][2];
  __shared__ float fu[64][12];
  const int tid = threadIdx.x;
  const int bid = blockIdx.x;
  const int b = bid / N_, n = bid - N_ * b;
  const size_t base = ((size_t)b * 64) * NT + n * 12;
  if (tid < 192) {
    int c = tid / 3, ch = tid - 3 * (tid / 3);
    *(float4*)&xr[c][ch * 4] = *(const float4*)(x + base + (size_t)c * NT + ch * 4);
    *(float4*)&xq[c][ch * 4] = *(const float4*)(xst + base + (size_t)c * NT + ch * 4);
  }
  __syncthreads();
  // hidden: 192 threads, 4 o per thread, shared t
  if (tid < 192) {
    int oq = tid / 12, t = tid - 12 * (tid / 12);
    float a0 = 0, a1 = 0, a2 = 0, a3 = 0;
    const float* w0 = stw + (4 * oq) * 128;
    for (int i = 0; i < 64; i++) {
      float h = xr[i][t];
      a0 += h * w0[i]; a1 += h * w0[128 + i];
      a2 += h * w0[256 + i]; a3 += h * w0[384 + i];
    }
    for (int i = 0; i < 64; i++) {
      float h = xq[i][t];
      a0 += h * w0[64 + i]; a1 += h * w0[192 + i];
      a2 += h * w0[320 + i]; a3 += h * w0[448 + i];
    }
    float av[4] = {a0, a1, a2, a3};
#pragma unroll
    for (int k = 0; k < 4; k++) {
      int o = 4 * oq + k;
      float y = av[k] + stb[o];
      float sc = stg[o] / sqrtf(stv[o] + 1e-5f);
      hd[o][t] = (y - stm[o]) * sc + stbb[o];
    }
  }
  __syncthreads();
  // g1: 192 threads (4 o each); then g2 (tid<128, 2 o) and g3 (128..191, 2 o)
  if (tid < 192) {
    int oq = tid / 12, t = tid - 12 * (tid / 12);
    float s0 = 0, s1 = 0, s2 = 0, s3 = 0, u0 = 0, u1 = 0, u2 = 0, u3 = 0;
    const float* wsr = p1w + (4 * oq) * 64;
    for (int i = 0; i < 64; i++) {
      float h = hd[i][t];
      s0 += h * wsr[i]; s1 += h * wsr[64 + i];
      s2 += h * wsr[128 + i]; s3 += h * wsr[192 + i];
      u0 += h * wsr[4096 + i]; u1 += h * wsr[4096 + 64 + i];
      u2 += h * wsr[4096 + 128 + i]; u3 += h * wsr[4096 + 192 + i];
    }
    float sv[4] = {s0, s1, s2, s3}, uv[4] = {u0, u1, u2, u3};
#pragma unroll
    for (int k = 0; k < 4; k++) {
      int o = 4 * oq + k;
      g1s[o][t] = sigm(sv[k] + p1b[o]) * tanhf(uv[k] + p1b[o + 64]);
    }
  }
  if (tid < 128) {
    int oq = tid / 4, q = tid & 3;
    float s0 = 0, s1 = 0, u0 = 0, u1 = 0;
    const float* wsr = p2w + (2 * oq) * 192;
    for (int i = 0; i < 64; i++)
#pragma unroll
      for (int kk = 0; kk < 3; kk++) {
        float h = hd[i][3 * q + kk];
        s0 += h * wsr[i * 3 + kk]; s1 += h * wsr[192 + i * 3 + kk];
        u0 += h * wsr[12288 + i * 3 + kk]; u1 += h * wsr[12288 + 192 + i * 3 + kk];
      }
    int o = 2 * oq;
    g2s[o][q] = sigm(s0 + p2b[o]) * tanhf(u0 + p2b[o + 64]);
    g2s[o + 1][q] = sigm(s1 + p2b[o + 1]) * tanhf(u1 + p2b[o + 65]);
  } else if (tid < 192) {
    int r = tid - 128;
    int oq = r / 2, q = r & 1;
    float s0 = 0, s1 = 0, u0 = 0, u1 = 0;
    const float* wsr = p3w + (2 * oq) * 384;
    for (int i = 0; i < 64; i++)
#pragma unroll
      for (int kk = 0; kk < 6; kk++) {
        float h = hd[i][6 * q + kk];
        s0 += h * wsr[i * 6 + kk]; s1 += h * wsr[384 + i * 6 + kk];
        u0 += h * wsr[24576 + i * 6 + kk]; u1 += h * wsr[24576 + 384 + i * 6 + kk];
      }
    int o = 2 * oq;
    g3s[o][q] = sigm(s0 + p3b[o]) * tanhf(u0 + p3b[o + 64]);
    g3s[o + 1][q] = sigm(s1 + p3b[o + 1]) * tanhf(u1 + p3b[o + 65]);
  }
  __syncthreads();
  // fusion conv + pyr bn; residual bn -> new x
  if (tid < 192) {
    int oq = tid / 12, t = tid - 12 * (tid / 12);
    float a0 = 0, a1 = 0, a2 = 0, a3 = 0;
    const float* w0 = pcw + (4 * oq) * 192;
    for (int c = 0; c < 64; c++) {
      float v = g1s[c][t];
      a0 += v * w0[c]; a1 += v * w0[192 + c];
      a2 += v * w0[384 + c]; a3 += v * w0[576 + c];
    }
    float c4 = fminf(fmaxf((t - 1) * (1.f / 3.f), 0.f), 3.f);
    int q0 = (int)c4;
    float f4 = c4 - (float)q0;
    int q1 = min(q0 + 1, 3);
    for (int c = 0; c < 64; c++) {
      float v = (1.f - f4) * g2s[c][q0] + f4 * g2s[c][q1];
      a0 += v * w0[64 + c]; a1 += v * w0[192 + 64 + c];
      a2 += v * w0[384 + 64 + c]; a3 += v * w0[576 + 64 + c];
    }
    float f2 = fminf(fmaxf((2 * t - 5) * (1.f / 12.f), 0.f), 1.f);
    for (int c = 0; c < 64; c++) {
      float v = (1.f - f2) * g3s[c][0] + f2 * g3s[c][1];
      a0 += v * w0[128 + c]; a1 += v * w0[192 + 128 + c];
      a2 += v * w0[384 + 128 + c]; a3 += v * w0[576 + 128 + c];
    }
    float av[4] = {a0, a1, a2, a3};
#pragma unroll
    for (int k = 0; k < 4; k++) {
      int o = 4 * oq + k;
      float y = av[k] + pcb[o];
      float s1 = pbg[o] / sqrtf(pbv[o] + 1e-5f);
      float fv = (y - pbm[o]) * s1 + pbb[o];
      fu[o][t] = fv;
      float s2 = bng[o] / sqrtf(bnv[o] + 1e-5f);
      xr[o][t] = (fv + xr[o][t] - bnm[o]) * s2 + bnb[o];
    }
  }
  __syncthreads();
  if (tid < 192) {
    int c = tid / 3, ch = tid - 3 * (tid / 3);
    *(float4*)(x + base + (size_t)c * NT + ch * 4) = *(float4*)&xr[c][ch * 4];
  }
  if (tid < 128) {
    float a = skb[tid];
    const float* wr = skw + tid * 64;
    for (int c = 0; c < 64; c++) a += fu[c][11] * wr[c];
    size_t o = ((size_t)b * 128 + tid) * N_ + n;
    skipb[o] = accum ? (skipb[o] + a) : a;
  }
}

// ---------------- k6: end MLP per (b,n) — fp32 output ----------------
__global__ __launch_bounds__(256) void k6_end(const float* __restrict__ skip,
                                              const float* __restrict__ w1,
                                              const float* __restrict__ b1,
                                              const float* __restrict__ w2,
                                              const float* __restrict__ b2,
                                              float* __restrict__ out) {
  __shared__ float sk[128];
  __shared__ float h[256];
  const int blk = blockIdx.x;
  const int b = blk / N_;
  const int n = blk - N_ * b;
  const int tid = threadIdx.x;
  if (tid < 128) sk[tid] = fmaxf(skip[((size_t)b * 128 + tid) * N_ + n], 0.f);
  __syncthreads();
  {
    float a = b1[tid];
    for (int s = 0; s < 128; s++) a += w1[tid * 128 + s] * sk[s];
    h[tid] = fmaxf(a, 0.f);
  }
  __syncthreads();
  if (tid < 12) {
    float a = b2[tid];
    for (int e = 0; e < 256; e++) a += w2[tid * 256 + e] * h[e];
    out[((size_t)b * 12 + tid) * N_ + n] = a;
  }
}

// ---------------- host ----------------
extern "C" void kernel_launch(void* const* d_in, const int* in_sizes, int n_in,
                              void* d_out, int out_size, void* d_ws, size_t ws_size,
                              hipStream_t stream) {
  (void)in_sizes; (void)n_in;
  if (ws_size < (size_t)44 * 1024 * 1024) {
    k_sentinel<<<(out_size + 255) / 256, 256, 0, stream>>>((float*)d_out, out_size);
    return;
  }
  const float* src = (const float*)d_in[0];
  const int* TE = (const int*)d_in[1];
  const float* sp = (const float*)d_in[2];
  const float* tp = (const float*)d_in[3];
  const float* SE = (const float*)d_in[4];
  const float* tmlp1_w = (const float*)d_in[5];
  const float* tmlp1_b = (const float*)d_in[6];
  const float* tmlp2_w = (const float*)d_in[7];
  const float* tmlp2_b = (const float*)d_in[8];
  const float* smlp1_w = (const float*)d_in[9];
  const float* smlp1_b = (const float*)d_in[10];
  const float* smlp2_w = (const float*)d_in[11];
  const float* smlp2_b = (const float*)d_in[12];
  const float* start_w = (const float*)d_in[13];
  const float* start_b = (const float*)d_in[14];
  const float* th1w = (const float*)d_in[15];
  const float* th1b = (const float*)d_in[16];
  const float* th2w = (const float*)d_in[17];
  const float* th2b = (const float*)d_in[18];
  const float* stw = (const float*)d_in[19];
  const float* stb = (const float*)d_in[20];
  const float* stg = (const float*)d_in[21];
  const float* stbb = (const float*)d_in[22];
  const float* stm = (const float*)d_in[23];
  const float* stv = (const float*)d_in[24];
  const float* p1w = (const float*)d_in[25];
  const float* p1b = (const float*)d_in[26];
  const float* p2w = (const float*)d_in[27];
  const float* p2b = (const float*)d_in[28];
  const float* p3w = (const float*)d_in[29];
  const float* p3b = (const float*)d_in[30];
  const float* pcw = (const float*)d_in[31];
  const float* pcb = (const float*)d_in[32];
  const float* pbg = (const float*)d_in[33];
  const float* pbb = (const float*)d_in[34];
  const float* pbm = (const float*)d_in[35];
  const float* pbv = (const float*)d_in[36];
  const float* skw = (const float*)d_in[37];
  const float* skb = (const float*)d_in[38];
  const float* bng = (const float*)d_in[39];
  const float* bnb = (const float*)d_in[40];
  const float* bnm = (const float*)d_in[41];
  const float* bnv = (const float*)d_in[42];
  const float* e1w = (const float*)d_in[43];
  const float* e1b = (const float*)d_in[44];
  const float* e2w = (const float*)d_in[45];
  const float* e2b = (const float*)d_in[46];

  float* ws = (float*)d_ws;
  float* coef = ws + 0;              // 2*8*66
  float* LsT  = ws + 8192;           // 325*328
  float* x    = ws + 4194304;        // [B,64,N,T]
  float* xst  = ws + 6291456;        // x_st
  float* skipb= ws + 10485760;       // [B,128,N]

  k0_convert<<<(N_ * LSP + 255) / 256, 256, 0, stream>>>(sp, LsT);
  k1_embed<<<1, 256, 0, stream>>>(TE, SE, tmlp1_w, tmlp1_b, tmlp2_w, tmlp2_b,
                                  smlp1_w, smlp1_b, smlp2_w, smlp2_b,
                                  th1w, th1b, th2w, th2b, coef);
  k2_start<<<(B_ * C_ * NT + 255) / 256, 256, 0, stream>>>(src, start_w, start_b, x);

  for (int l = 0; l < 2; l++) {
    k3_basis<<<512, 512, 0, stream>>>(x, LsT, tp, coef + l * 528, xst);
    k45_layer<<<B_ * N_, 256, 0, stream>>>(
        x, xst,
        stw + l * 8192, stb + l * 64, stg + l * 64, stbb + l * 64,
        stm + l * 64, stv + l * 64,
        p1w + l * 8192, p1b + l * 128,
        p2w + l * 24576, p2b + l * 128,
        p3w + l * 49152, p3b + l * 128,
        pcw + l * 12288, pcb + l * 64,
        pbg + l * 64, pbb + l * 64, pbm + l * 64, pbv + l * 64,
        bng + l * 64, bnb + l * 64, bnm + l * 64, bnv + l * 64,
        skw + l * 8192, skb + l * 128,
        skipb, l);
  }
  k6_end<<<B_ * N_, 256, 0, stream>>>(skipb, e1w, e1b, e2w, e2b, (float*)d_out);
}

// Round 10
// 1523.907 us; speedup vs baseline: 1.1130x; 1.1130x over previous
//
#include <hip/hip_runtime.h>
#include <hip/hip_bf16.h>
#include <math.h>

// ---------------- problem constants ----------------
#define B_   8
#define T_   12
#define N_   325
#define C_   64
#define NT   3900     // N_*T_
#define LSP  328      // padded row stride of transposed sp matrix

__device__ __forceinline__ float sigm(float x) { return 1.f / (1.f + expf(-x)); }

// 512-thread (8-wave) multi-value reduction; ONE barrier (caller ping-pongs redb)
__device__ __forceinline__ void redN(float* v, int nv, float (*redb)[4], int tid) {
#pragma unroll
  for (int off = 1; off < 64; off <<= 1) {
    for (int i = 0; i < nv; i++) v[i] += __shfl_xor(v[i], off, 64);
  }
  if ((tid & 63) == 0) {
    for (int i = 0; i < nv; i++) redb[tid >> 6][i] = v[i];
  }
  __syncthreads();
  for (int i = 0; i < nv; i++) {
    float s = 0.f;
#pragma unroll
    for (int w = 0; w < 8; w++) s += redb[w][i];
    v[i] = s;
  }
}

// ---------------- sentinel (ws too small diagnostic) ----------------
__global__ __launch_bounds__(256) void k_sentinel(float* out, int n) {
  int i = blockIdx.x * 256 + threadIdx.x;
  if (i < n) out[i] = 7.0f;
}

// ---------------- k0: transpose sp (padded) ----------------
__global__ __launch_bounds__(256) void k0_convert(const float* __restrict__ sp,
                                                  float* __restrict__ LsT) {
  int idx = blockIdx.x * 256 + threadIdx.x;
  if (idx < N_ * LSP) {
    int m = idx / LSP, n = idx - m * LSP;
    LsT[idx] = (n < N_) ? sp[n * N_ + m] : 0.f;   // LsT[m][n] = Ls[n][m]
  }
}

// ---------------- k1: embeddings + theta coefficients ----------------
__global__ __launch_bounds__(256) void k1_embed(
    const int* __restrict__ TE, const float* __restrict__ SE,
    const float* __restrict__ w1, const float* __restrict__ b1,
    const float* __restrict__ w2, const float* __restrict__ b2,
    const float* __restrict__ sw1, const float* __restrict__ sb1,
    const float* __restrict__ sw2, const float* __restrict__ sb2,
    const float* __restrict__ t1w, const float* __restrict__ t1b,
    const float* __restrict__ t2w, const float* __restrict__ t2b,
    float* __restrict__ coef) {
  __shared__ float te2[8][10][12];
  __shared__ float ste[8][5][10];
  __shared__ float se1[5][10];
  __shared__ float se2[5][10];
  __shared__ float th[8][6][10];
  __shared__ int te64;
  const int tid = threadIdx.x;
  if (tid == 0) {
    int nz = 0;
    for (int k2 = 0; k2 < 96; k2++) nz += (TE[2 * k2 + 1] != 0) ? 1 : 0;
    te64 = (nz == 0) ? 1 : 0;
  }
  __syncthreads();
  for (int idx = tid; idx < 960; idx += 256) {
    int t = idx % 12, o = (idx / 12) % 10, b = idx / 120;
    int q = (b * 12 + t) * 2;
    int d = (te64 ? TE[2 * q] : TE[q]) % 7;
    int h = (te64 ? TE[2 * q + 2] : TE[q + 1]) % 288;
    float v = w1[o * 295 + d] + w1[o * 295 + 7 + h] + b1[o];
    te2[b][o][t] = fmaxf(v, 0.f);
  }
  __syncthreads();
  for (int idx = tid; idx < 400; idx += 256) {
    int s = idx % 10, o = (idx / 10) % 5, b = idx / 50;
    float a = b2[o];
    for (int t = 0; t < 12; t++) a += te2[b][s][t] * w2[o * 12 + t];
    ste[b][o][s] = fmaxf(a, 0.f);
  }
  if (tid < 50) {
    int o = tid / 10, j = tid % 10;
    float a = sb1[o];
    for (int n = 0; n < N_; n++) a += sw1[o * N_ + n] * SE[n * 10 + j];
    se1[o][j] = fmaxf(a, 0.f);
  }
  __syncthreads();
  if (tid < 50) {
    int t = tid / 10, s = tid % 10;
    float a = sb2[s];
    for (int j = 0; j < 10; j++) a += sw2[s * 10 + j] * se1[t][j];
    se2[t][s] = fmaxf(a, 0.f);
  }
  __syncthreads();
  for (int idx = tid; idx < 400; idx += 256) {
    int s = idx % 10, o = (idx / 10) % 5, b = idx / 50;
    ste[b][o][s] = fmaxf(se2[o][s] + ste[b][o][s], 0.f);
  }
  __syncthreads();
  for (int l = 0; l < 2; l++) {
    for (int idx = tid; idx < 480; idx += 256) {
      int s = idx % 10, q = (idx / 10) % 6, b = idx / 60;
      float a = t1b[l * 6 + q];
      for (int t = 0; t < 5; t++) a += ste[b][t][s] * t1w[(l * 6 + q) * 5 + t];
      th[b][q][s] = a;
    }
    __syncthreads();
    for (int idx = tid; idx < 528; idx += 256) {
      int q = idx % 6, p = (idx / 6) % 11, b = idx / 66;
      float a = t2b[l * 11 + p];
      for (int s = 0; s < 10; s++) a += th[b][q][s] * t2w[(l * 11 + p) * 10 + s];
      coef[(l * 8 + b) * 66 + q * 11 + p] = fmaxf(a, 0.f);
    }
    __syncthreads();
  }
}

// ---------------- k2: start 1x1 conv ----------------
__global__ __launch_bounds__(256) void k2_start(const float* __restrict__ src,
                                                const float* __restrict__ w,
                                                const float* __restrict__ bia,
                                                float* __restrict__ x) {
  int idx = blockIdx.x * 256 + threadIdx.x;
  if (idx >= B_ * C_ * NT) return;
  int pos = idx % NT, r = idx / NT, c = r & 63, b = r >> 6;
  int n = pos / 12, t = pos - 12 * n;
  float s = src[(b * 12 + t) * N_ + n];
  x[idx] = s * w[c] + bia[c];
}

// ---------------- k3: fused basis recursion + x_st accumulation ----------------
// Spatial: thread = (row-oct rq<41, t-quad, mm-quarter mq<4) = 492 active.
// 32 FMA per iteration over 82 mm; partials combined via LDS scratch. All 8
// waves active. Temporal: register-resident tridiagonal chain; norm fused via
// Pythagoras (one reduction/step).
__global__ __launch_bounds__(512, 4) void k3_basis(
    const float* __restrict__ x, const float* __restrict__ LsT,
    const float* __restrict__ tp, const float* __restrict__ coef,
    float* __restrict__ xst) {
  __shared__ float sb[2][3940];        // 328 rows x 12 (rows 325..327 stay 0)
  __shared__ float scr[8][369][4];     // matmul partial-combine scratch
  __shared__ float sred[2][8][4];
  const int tid = threadIdx.x;
  const int bc = blockIdx.x;
  const float* cf = coef + (bc >> 6) * 66;
  const float* xs = x + (size_t)bc * NT;
  float* xo = xst + (size_t)bc * NT;

  // spatial mapping
  const int sq = tid / 3, tq = tid - 3 * sq;
  const int mq = sq / 41, rq = sq - 41 * mq;
  const bool actS = (sq < 164);
  const bool mq0 = actS && (mq == 0);
  const int n0 = rq * 8, t0 = tq * 4;
  const int mm0 = mq * 82;
  const int mm1 = (mq == 3) ? 325 : (mm0 + 82);
  const int e0 = n0 * 12 + t0;
  const int cid = rq * 3 + tq;         // combine index for mq0 threads

  // temporal layout
  const bool actT = (tid < N_);
  const int rowOff = tid * 12;

  float w[11];
#pragma unroll
  for (int k = 0; k < 11; k++) w[k] = tp[k * 12 + k + 1];

  float last[12], sec[12], acc[12], rr[12];
  int p = 0, m = 0, spc = 0;

  // zero sb pad rows (325..327 of both buffers)
  if (tid < 80) {
    int bsel = tid / 40, off = tid - 40 * bsel;
    sb[bsel][3900 + off] = 0.f;
  }

  // ---- m00 = unit(residual slice) (temporal layout) ----
  {
    float np = 0.f;
#pragma unroll
    for (int u = 0; u < 12; u++) rr[u] = 0.f;
    if (actT) {
      const float4 a = *(const float4*)(xs + rowOff);
      const float4 b4 = *(const float4*)(xs + rowOff + 4);
      const float4 c4 = *(const float4*)(xs + rowOff + 8);
      rr[0] = a.x; rr[1] = a.y; rr[2] = a.z; rr[3] = a.w;
      rr[4] = b4.x; rr[5] = b4.y; rr[6] = b4.z; rr[7] = b4.w;
      rr[8] = c4.x; rr[9] = c4.y; rr[10] = c4.z; rr[11] = c4.w;
#pragma unroll
      for (int u = 0; u < 12; u++) np += rr[u] * rr[u];
    }
    p ^= 1; redN(&np, 1, sred[p], tid);
    const float inv = 1.f / fmaxf(sqrtf(np), 1e-8f);
    const float c0 = cf[m]; m++;
#pragma unroll
    for (int u = 0; u < 12; u++) {
      last[u] = rr[u] * inv;
      acc[u] = c0 * last[u];
      sec[u] = 0.f;
    }
    if (actT) {
      float4 wv;
      wv.x = last[0]; wv.y = last[1]; wv.z = last[2]; wv.w = last[3];
      *(float4*)&sb[0][rowOff] = wv;
      wv.x = last[4]; wv.y = last[5]; wv.z = last[6]; wv.w = last[7];
      *(float4*)&sb[0][rowOff + 4] = wv;
      wv.x = last[8]; wv.y = last[9]; wv.z = last[10]; wv.w = last[11];
      *(float4*)&sb[0][rowOff + 8] = wv;
    }
    __syncthreads();
  }

  for (int i = 0; i <= 10; i++) {
    if (i > 0) {
      // ---------- spatial step: last_s = sb[spc], sec_s = sb[sps] ----------
      const int sps = 1 - spc;
      const bool hasSec = (i >= 2);
      float rt[8][4];
#pragma unroll
      for (int ii = 0; ii < 8; ii++)
#pragma unroll
        for (int j = 0; j < 4; j++) rt[ii][j] = 0.f;
      if (actS) {
        const float* lpc = LsT + n0;
        const float* sc = &sb[spc][t0];
#pragma unroll 2
        for (int mm = mm0; mm < mm1; mm++) {
          const float4 a0 = *(const float4*)(lpc + mm * LSP);
          const float4 a1 = *(const float4*)(lpc + mm * LSP + 4);
          const float4 mr = *(const float4*)(sc + mm * 12);
          rt[0][0] += a0.x * mr.x; rt[0][1] += a0.x * mr.y; rt[0][2] += a0.x * mr.z; rt[0][3] += a0.x * mr.w;
          rt[1][0] += a0.y * mr.x; rt[1][1] += a0.y * mr.y; rt[1][2] += a0.y * mr.z; rt[1][3] += a0.y * mr.w;
          rt[2][0] += a0.z * mr.x; rt[2][1] += a0.z * mr.y; rt[2][2] += a0.z * mr.z; rt[2][3] += a0.z * mr.w;
          rt[3][0] += a0.w * mr.x; rt[3][1] += a0.w * mr.y; rt[3][2] += a0.w * mr.z; rt[3][3] += a0.w * mr.w;
          rt[4][0] += a1.x * mr.x; rt[4][1] += a1.x * mr.y; rt[4][2] += a1.x * mr.z; rt[4][3] += a1.x * mr.w;
          rt[5][0] += a1.y * mr.x; rt[5][1] += a1.y * mr.y; rt[5][2] += a1.y * mr.z; rt[5][3] += a1.y * mr.w;
          rt[6][0] += a1.z * mr.x; rt[6][1] += a1.z * mr.y; rt[6][2] += a1.z * mr.z; rt[6][3] += a1.z * mr.w;
          rt[7][0] += a1.w * mr.x; rt[7][1] += a1.w * mr.y; rt[7][2] += a1.w * mr.z; rt[7][3] += a1.w * mr.w;
        }
      }
      // combine partials: mq>0 write, mq0 accumulate
      if (actS && mq > 0) {
        const int widx = (mq - 1) * 123 + cid;
#pragma unroll
        for (int ii = 0; ii < 8; ii++) {
          float4 wv;
          wv.x = rt[ii][0]; wv.y = rt[ii][1]; wv.z = rt[ii][2]; wv.w = rt[ii][3];
          *(float4*)&scr[ii][widx][0] = wv;
        }
      }
      __syncthreads();
      float v3[3] = {0.f, 0.f, 0.f};
      if (mq0) {
#pragma unroll
        for (int kk = 0; kk < 3; kk++) {
          const int ridx = kk * 123 + cid;
#pragma unroll
          for (int ii = 0; ii < 8; ii++) {
            const float4 q = *(const float4*)&scr[ii][ridx][0];
            rt[ii][0] += q.x; rt[ii][1] += q.y; rt[ii][2] += q.z; rt[ii][3] += q.w;
          }
        }
        // dot-product partials: A=<r,l>, B=<r,s>, C=<l,s>
#pragma unroll
        for (int ii = 0; ii < 8; ii++) {
          const float4 lq = *(const float4*)&sb[spc][e0 + ii * 12];
          v3[0] += rt[ii][0] * lq.x + rt[ii][1] * lq.y + rt[ii][2] * lq.z + rt[ii][3] * lq.w;
          if (hasSec) {
            const float4 sq4 = *(const float4*)&sb[sps][e0 + ii * 12];
            v3[1] += rt[ii][0] * sq4.x + rt[ii][1] * sq4.y + rt[ii][2] * sq4.z + rt[ii][3] * sq4.w;
            v3[2] += lq.x * sq4.x + lq.y * sq4.y + lq.z * sq4.z + lq.w * sq4.w;
          }
        }
      }
      p ^= 1;
      if (hasSec) redN(v3, 3, sred[p], tid); else redN(v3, 1, sred[p], tid);
      const float d1 = v3[0];
      const float d2 = hasSec ? (v3[1] - d1 * v3[2]) : 0.f;
      float np = 0.f;
      if (mq0) {
#pragma unroll
        for (int ii = 0; ii < 8; ii++) {
          const float4 lq = *(const float4*)&sb[spc][e0 + ii * 12];
          float sx = 0.f, sy = 0.f, sz = 0.f, sw = 0.f;
          if (hasSec) {
            const float4 sq4 = *(const float4*)&sb[sps][e0 + ii * 12];
            sx = sq4.x; sy = sq4.y; sz = sq4.z; sw = sq4.w;
          }
          rt[ii][0] -= d1 * lq.x + d2 * sx;
          rt[ii][1] -= d1 * lq.y + d2 * sy;
          rt[ii][2] -= d1 * lq.z + d2 * sz;
          rt[ii][3] -= d1 * lq.w + d2 * sw;
          np += rt[ii][0] * rt[ii][0] + rt[ii][1] * rt[ii][1] +
                rt[ii][2] * rt[ii][2] + rt[ii][3] * rt[ii][3];
        }
      }
      p ^= 1; redN(&np, 1, sred[p], tid);
      const float inv = 1.f / fmaxf(sqrtf(np), 1e-8f);
      const float cs = cf[m]; m++;
      if (mq0) {
#pragma unroll
        for (int ii = 0; ii < 8; ii++) {
          float4 wv;
          wv.x = rt[ii][0] * inv; wv.y = rt[ii][1] * inv;
          wv.z = rt[ii][2] * inv; wv.w = rt[ii][3] * inv;
          *(float4*)&sb[sps][e0 + ii * 12] = wv;   // pad rows write 0
        }
      }
      spc = sps;
      __syncthreads();
      // temporal-layout init: load new M_i0 row; acc += c*row; sec <- 0
      if (actT) {
        const float4 a = *(const float4*)&sb[spc][rowOff];
        const float4 b4 = *(const float4*)&sb[spc][rowOff + 4];
        const float4 c4 = *(const float4*)&sb[spc][rowOff + 8];
        last[0] = a.x; last[1] = a.y; last[2] = a.z; last[3] = a.w;
        last[4] = b4.x; last[5] = b4.y; last[6] = b4.z; last[7] = b4.w;
        last[8] = c4.x; last[9] = c4.y; last[10] = c4.z; last[11] = c4.w;
#pragma unroll
        for (int u = 0; u < 12; u++) {
          acc[u] += cs * last[u];
          sec[u] = 0.f;
        }
      }
    }
    // ---------- temporal chain (5 steps), one fused reduction per step ------
    for (int j5 = 0; j5 < 5; j5++) {
      float v4[4] = {0.f, 0.f, 0.f, 0.f};
      if (actT) {
#pragma unroll
        for (int u = 0; u < 12; u++) {
          float r = 0.f;
          if (u > 0) r += last[u - 1] * w[u - 1];
          if (u < 11) r += last[u + 1] * w[u];
          rr[u] = r;
          v4[0] += r * last[u];
          v4[1] += r * sec[u];
          v4[2] += last[u] * sec[u];
          v4[3] += r * r;
        }
      }
      p ^= 1; redN(v4, 4, sred[p], tid);
      const float d1 = v4[0];
      const float d2 = v4[1] - d1 * v4[2];
      // ||r - d1 l - d2 s||^2 = ||r||^2 - d1^2 - d2^2  (l,s unit, <l,s>~0)
      const float np = fmaxf(v4[3] - d1 * d1 - d2 * d2, 0.f);
      const float inv = 1.f / fmaxf(sqrtf(np), 1e-8f);
      const float c = cf[m]; m++;
      if (actT) {
#pragma unroll
        for (int u = 0; u < 12; u++) {
          const float v = (rr[u] - d1 * last[u] - d2 * sec[u]) * inv;
          sec[u] = last[u];
          last[u] = v;
          acc[u] += c * v;
        }
      }
    }
  }
  if (actT) {
    float4 wv;
    wv.x = acc[0]; wv.y = acc[1]; wv.z = acc[2]; wv.w = acc[3];
    *(float4*)(xo + rowOff) = wv;
    wv.x = acc[4]; wv.y = acc[5]; wv.z = acc[6]; wv.w = acc[7];
    *(float4*)(xo + rowOff + 4) = wv;
    wv.x = acc[8]; wv.y = acc[9]; wv.z = acc[10]; wv.w = acc[11];
    *(float4*)(xo + rowOff + 8) = wv;
  }
}

// ---------------- k45: fused layer body, one block per (b,n) ----------------
__global__ __launch_bounds__(256) void k45_layer(
    float* __restrict__ x, const float* __restrict__ xst,
    const float* __restrict__ stw, const float* __restrict__ stb,
    const float* __restrict__ stg, const float* __restrict__ stbb,
    const float* __restrict__ stm, const float* __restrict__ stv,
    const float* __restrict__ p1w, const float* __restrict__ p1b,
    const float* __restrict__ p2w, const float* __restrict__ p2b,
    const float* __restrict__ p3w, const float* __restrict__ p3b,
    const float* __restrict__ pcw, const float* __restrict__ pcb,
    const float* __restrict__ pbg, const float* __restrict__ pbb,
    const float* __restrict__ pbm, const float* __restrict__ pbv,
    const float* __restrict__ bng, const float* __restrict__ bnb,
    const float* __restrict__ bnm, const float* __restrict__ bnv,
    const float* __restrict__ skw, const float* __restrict__ skb,
    float* __restrict__ skipb, int accum) {
  __shared__ float xr[64][12];
  __shared__ float xq[64][12];
  __shared__ float hd[64][12];
  __shared__ float g1s[64][12];
  __shared__ float g2s[64][4];
  __shared__ float g3s[64][2];
  __shared__ float fu[64][12];
  const int tid = threadIdx.x;
  const int bid = blockIdx.x;
  const int b = bid / N_, n = bid - N_ * b;
  const size_t base = ((size_t)b * 64) * NT + n * 12;
  if (tid < 192) {
    int c = tid / 3, ch = tid - 3 * (tid / 3);
    *(float4*)&xr[c][ch * 4] = *(const float4*)(x + base + (size_t)c * NT + ch * 4);
    *(float4*)&xq[c][ch * 4] = *(const float4*)(xst + base + (size_t)c * NT + ch * 4);
  }
  __syncthreads();
  if (tid < 192) {
    int oq = tid / 12, t = tid - 12 * (tid / 12);
    float a0 = 0, a1 = 0, a2 = 0, a3 = 0;
    const float* w0 = stw + (4 * oq) * 128;
    for (int i = 0; i < 64; i++) {
      float h = xr[i][t];
      a0 += h * w0[i]; a1 += h * w0[128 + i];
      a2 += h * w0[256 + i]; a3 += h * w0[384 + i];
    }
    for (int i = 0; i < 64; i++) {
      float h = xq[i][t];
      a0 += h * w0[64 + i]; a1 += h * w0[192 + i];
      a2 += h * w0[320 + i]; a3 += h * w0[448 + i];
    }
    float av[4] = {a0, a1, a2, a3};
#pragma unroll
    for (int k = 0; k < 4; k++) {
      int o = 4 * oq + k;
      float y = av[k] + stb[o];
      float sc = stg[o] / sqrtf(stv[o] + 1e-5f);
      hd[o][t] = (y - stm[o]) * sc + stbb[o];
    }
  }
  __syncthreads();
  if (tid < 192) {
    int oq = tid / 12, t = tid - 12 * (tid / 12);
    float s0 = 0, s1 = 0, s2 = 0, s3 = 0, u0 = 0, u1 = 0, u2 = 0, u3 = 0;
    const float* wsr = p1w + (4 * oq) * 64;
    for (int i = 0; i < 64; i++) {
      float h = hd[i][t];
      s0 += h * wsr[i]; s1 += h * wsr[64 + i];
      s2 += h * wsr[128 + i]; s3 += h * wsr[192 + i];
      u0 += h * wsr[4096 + i]; u1 += h * wsr[4096 + 64 + i];
      u2 += h * wsr[4096 + 128 + i]; u3 += h * wsr[4096 + 192 + i];
    }
    float sv[4] = {s0, s1, s2, s3}, uv[4] = {u0, u1, u2, u3};
#pragma unroll
    for (int k = 0; k < 4; k++) {
      int o = 4 * oq + k;
      g1s[o][t] = sigm(sv[k] + p1b[o]) * tanhf(uv[k] + p1b[o + 64]);
    }
  }
  if (tid < 128) {
    int oq = tid / 4, q = tid & 3;
    float s0 = 0, s1 = 0, u0 = 0, u1 = 0;
    const float* wsr = p2w + (2 * oq) * 192;
    for (int i = 0; i < 64; i++)
#pragma unroll
      for (int kk = 0; kk < 3; kk++) {
        float h = hd[i][3 * q + kk];
        s0 += h * wsr[i * 3 + kk]; s1 += h * wsr[192 + i * 3 + kk];
        u0 += h * wsr[12288 + i * 3 + kk]; u1 += h * wsr[12288 + 192 + i * 3 + kk];
      }
    int o = 2 * oq;
    g2s[o][q] = sigm(s0 + p2b[o]) * tanhf(u0 + p2b[o + 64]);
    g2s[o + 1][q] = sigm(s1 + p2b[o + 1]) * tanhf(u1 + p2b[o + 65]);
  } else if (tid < 192) {
    int r = tid - 128;
    int oq = r / 2, q = r & 1;
    float s0 = 0, s1 = 0, u0 = 0, u1 = 0;
    const float* wsr = p3w + (2 * oq) * 384;
    for (int i = 0; i < 64; i++)
#pragma unroll
      for (int kk = 0; kk < 6; kk++) {
        float h = hd[i][6 * q + kk];
        s0 += h * wsr[i * 6 + kk]; s1 += h * wsr[384 + i * 6 + kk];
        u0 += h * wsr[24576 + i * 6 + kk]; u1 += h * wsr[24576 + 384 + i * 6 + kk];
      }
    int o = 2 * oq;
    g3s[o][q] = sigm(s0 + p3b[o]) * tanhf(u0 + p3b[o + 64]);
    g3s[o + 1][q] = sigm(s1 + p3b[o + 1]) * tanhf(u1 + p3b[o + 65]);
  }
  __syncthreads();
  if (tid < 192) {
    int oq = tid / 12, t = tid - 12 * (tid / 12);
    float a0 = 0, a1 = 0, a2 = 0, a3 = 0;
    const float* w0 = pcw + (4 * oq) * 192;
    for (int c = 0; c < 64; c++) {
      float v = g1s[c][t];
      a0 += v * w0[c]; a1 += v * w0[192 + c];
      a2 += v * w0[384 + c]; a3 += v * w0[576 + c];
    }
    float c4 = fminf(fmaxf((t - 1) * (1.f / 3.f), 0.f), 3.f);
    int q0 = (int)c4;
    float f4 = c4 - (float)q0;
    int q1 = min(q0 + 1, 3);
    for (int c = 0; c < 64; c++) {
      float v = (1.f - f4) * g2s[c][q0] + f4 * g2s[c][q1];
      a0 += v * w0[64 + c]; a1 += v * w0[192 + 64 + c];
      a2 += v * w0[384 + 64 + c]; a3 += v * w0[576 + 64 + c];
    }
    float f2 = fminf(fmaxf((2 * t - 5) * (1.f / 12.f), 0.f), 1.f);
    for (int c = 0; c < 64; c++) {
      float v = (1.f - f2) * g3s[c][0] + f2 * g3s[c][1];
      a0 += v * w0[128 + c]; a1 += v * w0[192 + 128 + c];
      a2 += v * w0[384 + 128 + c]; a3 += v * w0[576 + 128 + c];
    }
    float av[4] = {a0, a1, a2, a3};
#pragma unroll
    for (int k = 0; k < 4; k++) {
      int o = 4 * oq + k;
      float y = av[k] + pcb[o];
      float s1 = pbg[o] / sqrtf(pbv[o] + 1e-5f);
      float fv = (y - pbm[o]) * s1 + pbb[o];
      fu[o][t] = fv;
      float s2 = bng[o] / sqrtf(bnv[o] + 1e-5f);
      xr[o][t] = (fv + xr[o][t] - bnm[o]) * s2 + bnb[o];
    }
  }
  __syncthreads();
  if (tid < 192) {
    int c = tid / 3, ch = tid - 3 * (tid / 3);
    *(float4*)(x + base + (size_t)c * NT + ch * 4) = *(float4*)&xr[c][ch * 4];
  }
  if (tid < 128) {
    float a = skb[tid];
    const float* wr = skw + tid * 64;
    for (int c = 0; c < 64; c++) a += fu[c][11] * wr[c];
    size_t o = ((size_t)b * 128 + tid) * N_ + n;
    skipb[o] = accum ? (skipb[o] + a) : a;
  }
}

// ---------------- k6: end MLP per (b,n) — fp32 output ----------------
__global__ __launch_bounds__(256) void k6_end(const float* __restrict__ skip,
                                              const float* __restrict__ w1,
                                              const float* __restrict__ b1,
                                              const float* __restrict__ w2,
                                              const float* __restrict__ b2,
                                              float* __restrict__ out) {
  __shared__ float sk[128];
  __shared__ float h[256];
  const int blk = blockIdx.x;
  const int b = blk / N_;
  const int n = blk - N_ * b;
  const int tid = threadIdx.x;
  if (tid < 128) sk[tid] = fmaxf(skip[((size_t)b * 128 + tid) * N_ + n], 0.f);
  __syncthreads();
  {
    float a = b1[tid];
    for (int s = 0; s < 128; s++) a += w1[tid * 128 + s] * sk[s];
    h[tid] = fmaxf(a, 0.f);
  }
  __syncthreads();
  if (tid < 12) {
    float a = b2[tid];
    for (int e = 0; e < 256; e++) a += w2[tid * 256 + e] * h[e];
    out[((size_t)b * 12 + tid) * N_ + n] = a;
  }
}

// ---------------- host ----------------
extern "C" void kernel_launch(void* const* d_in, const int* in_sizes, int n_in,
                              void* d_out, int out_size, void* d_ws, size_t ws_size,
                              hipStream_t stream) {
  (void)in_sizes; (void)n_in;
  if (ws_size < (size_t)44 * 1024 * 1024) {
    k_sentinel<<<(out_size + 255) / 256, 256, 0, stream>>>((float*)d_out, out_size);
    return;
  }
  const float* src = (const float*)d_in[0];
  const int* TE = (const int*)d_in[1];
  const float* sp = (const float*)d_in[2];
  const float* tp = (const float*)d_in[3];
  const float* SE = (const float*)d_in[4];
  const float* tmlp1_w = (const float*)d_in[5];
  const float* tmlp1_b = (const float*)d_in[6];
  const float* tmlp2_w = (const float*)d_in[7];
  const float* tmlp2_b = (const float*)d_in[8];
  const float* smlp1_w = (const float*)d_in[9];
  const float* smlp1_b = (const float*)d_in[10];
  const float* smlp2_w = (const float*)d_in[11];
  const float* smlp2_b = (const float*)d_in[12];
  const float* start_w = (const float*)d_in[13];
  const float* start_b = (const float*)d_in[14];
  const float* th1w = (const float*)d_in[15];
  const float* th1b = (const float*)d_in[16];
  const float* th2w = (const float*)d_in[17];
  const float* th2b = (const float*)d_in[18];
  const float* stw = (const float*)d_in[19];
  const float* stb = (const float*)d_in[20];
  const float* stg = (const float*)d_in[21];
  const float* stbb = (const float*)d_in[22];
  const float* stm = (const float*)d_in[23];
  const float* stv = (const float*)d_in[24];
  const float* p1w = (const float*)d_in[25];
  const float* p1b = (const float*)d_in[26];
  const float* p2w = (const float*)d_in[27];
  const float* p2b = (const float*)d_in[28];
  const float* p3w = (const float*)d_in[29];
  const float* p3b = (const float*)d_in[30];
  const float* pcw = (const float*)d_in[31];
  const float* pcb = (const float*)d_in[32];
  const float* pbg = (const float*)d_in[33];
  const float* pbb = (const float*)d_in[34];
  const float* pbm = (const float*)d_in[35];
  const float* pbv = (const float*)d_in[36];
  const float* skw = (const float*)d_in[37];
  const float* skb = (const float*)d_in[38];
  const float* bng = (const float*)d_in[39];
  const float* bnb = (const float*)d_in[40];
  const float* bnm = (const float*)d_in[41];
  const float* bnv = (const float*)d_in[42];
  const float* e1w = (const float*)d_in[43];
  const float* e1b = (const float*)d_in[44];
  const float* e2w = (const float*)d_in[45];
  const float* e2b = (const float*)d_in[46];

  float* ws = (float*)d_ws;
  float* coef = ws + 0;              // 2*8*66
  float* LsT  = ws + 8192;           // 325*328
  float* x    = ws + 4194304;        // [B,64,N,T]
  float* xst  = ws + 6291456;        // x_st
  float* skipb= ws + 10485760;       // [B,128,N]

  k0_convert<<<(N_ * LSP + 255) / 256, 256, 0, stream>>>(sp, LsT);
  k1_embed<<<1, 256, 0, stream>>>(TE, SE, tmlp1_w, tmlp1_b, tmlp2_w, tmlp2_b,
                                  smlp1_w, smlp1_b, smlp2_w, smlp2_b,
                                  th1w, th1b, th2w, th2b, coef);
  k2_start<<<(B_ * C_ * NT + 255) / 256, 256, 0, stream>>>(src, start_w, start_b, x);

  for (int l = 0; l < 2; l++) {
    k3_basis<<<512, 512, 0, stream>>>(x, LsT, tp, coef + l * 528, xst);
    k45_layer<<<B_ * N_, 256, 0, stream>>>(
        x, xst,
        stw + l * 8192, stb + l * 64, stg + l * 64, stbb + l * 64,
        stm + l * 64, stv + l * 64,
        p1w + l * 8192, p1b + l * 128,
        p2w + l * 24576, p2b + l * 128,
        p3w + l * 49152, p3b + l * 128,
        pcw + l * 12288, pcb + l * 64,
        pbg + l * 64, pbb + l * 64, pbm + l * 64, pbv + l * 64,
        bng + l * 64, bnb + l * 64, bnm + l * 64, bnv + l * 64,
        skw + l * 8192, skb + l * 128,
        skipb, l);
  }
  k6_end<<<B_ * N_, 256, 0, stream>>>(skipb, e1w, e1b, e2w, e2b, (float*)d_out);
}

// Round 11
// 1473.835 us; speedup vs baseline: 1.1508x; 1.0340x over previous
//
#include <hip/hip_runtime.h>
#include <hip/hip_bf16.h>
#include <math.h>

// ---------------- problem constants ----------------
#define B_   8
#define T_   12
#define N_   325
#define C_   64
#define NT   3900     // N_*T_
#define LSP  328      // padded row stride of transposed sp matrix

__device__ __forceinline__ float sigm(float x) { return 1.f / (1.f + expf(-x)); }

// 512-thread (8-wave) multi-value reduction; ONE barrier (caller ping-pongs redb)
__device__ __forceinline__ void redN(float* v, int nv, float (*redb)[4], int tid) {
#pragma unroll
  for (int off = 1; off < 64; off <<= 1) {
    for (int i = 0; i < nv; i++) v[i] += __shfl_xor(v[i], off, 64);
  }
  if ((tid & 63) == 0) {
    for (int i = 0; i < nv; i++) redb[tid >> 6][i] = v[i];
  }
  __syncthreads();
  for (int i = 0; i < nv; i++) {
    float s = 0.f;
#pragma unroll
    for (int w = 0; w < 8; w++) s += redb[w][i];
    v[i] = s;
  }
}

// ---------------- sentinel (ws too small diagnostic) ----------------
__global__ __launch_bounds__(256) void k_sentinel(float* out, int n) {
  int i = blockIdx.x * 256 + threadIdx.x;
  if (i < n) out[i] = 7.0f;
}

// ---------------- k0: transpose sp (padded) ----------------
__global__ __launch_bounds__(256) void k0_convert(const float* __restrict__ sp,
                                                  float* __restrict__ LsT) {
  int idx = blockIdx.x * 256 + threadIdx.x;
  if (idx < N_ * LSP) {
    int m = idx / LSP, n = idx - m * LSP;
    LsT[idx] = (n < N_) ? sp[n * N_ + m] : 0.f;   // LsT[m][n] = Ls[n][m]
  }
}

// ---------------- k1: embeddings + theta coefficients ----------------
__global__ __launch_bounds__(256) void k1_embed(
    const int* __restrict__ TE, const float* __restrict__ SE,
    const float* __restrict__ w1, const float* __restrict__ b1,
    const float* __restrict__ w2, const float* __restrict__ b2,
    const float* __restrict__ sw1, const float* __restrict__ sb1,
    const float* __restrict__ sw2, const float* __restrict__ sb2,
    const float* __restrict__ t1w, const float* __restrict__ t1b,
    const float* __restrict__ t2w, const float* __restrict__ t2b,
    float* __restrict__ coef) {
  __shared__ float te2[8][10][12];
  __shared__ float ste[8][5][10];
  __shared__ float se1[5][10];
  __shared__ float se2[5][10];
  __shared__ float th[8][6][10];
  __shared__ int te64;
  const int tid = threadIdx.x;
  if (tid == 0) {
    int nz = 0;
    for (int k2 = 0; k2 < 96; k2++) nz += (TE[2 * k2 + 1] != 0) ? 1 : 0;
    te64 = (nz == 0) ? 1 : 0;
  }
  __syncthreads();
  for (int idx = tid; idx < 960; idx += 256) {
    int t = idx % 12, o = (idx / 12) % 10, b = idx / 120;
    int q = (b * 12 + t) * 2;
    int d = (te64 ? TE[2 * q] : TE[q]) % 7;
    int h = (te64 ? TE[2 * q + 2] : TE[q + 1]) % 288;
    float v = w1[o * 295 + d] + w1[o * 295 + 7 + h] + b1[o];
    te2[b][o][t] = fmaxf(v, 0.f);
  }
  __syncthreads();
  for (int idx = tid; idx < 400; idx += 256) {
    int s = idx % 10, o = (idx / 10) % 5, b = idx / 50;
    float a = b2[o];
    for (int t = 0; t < 12; t++) a += te2[b][s][t] * w2[o * 12 + t];
    ste[b][o][s] = fmaxf(a, 0.f);
  }
  if (tid < 50) {
    int o = tid / 10, j = tid % 10;
    float a = sb1[o];
    for (int n = 0; n < N_; n++) a += sw1[o * N_ + n] * SE[n * 10 + j];
    se1[o][j] = fmaxf(a, 0.f);
  }
  __syncthreads();
  if (tid < 50) {
    int t = tid / 10, s = tid % 10;
    float a = sb2[s];
    for (int j = 0; j < 10; j++) a += sw2[s * 10 + j] * se1[t][j];
    se2[t][s] = fmaxf(a, 0.f);
  }
  __syncthreads();
  for (int idx = tid; idx < 400; idx += 256) {
    int s = idx % 10, o = (idx / 10) % 5, b = idx / 50;
    ste[b][o][s] = fmaxf(se2[o][s] + ste[b][o][s], 0.f);
  }
  __syncthreads();
  for (int l = 0; l < 2; l++) {
    for (int idx = tid; idx < 480; idx += 256) {
      int s = idx % 10, q = (idx / 10) % 6, b = idx / 60;
      float a = t1b[l * 6 + q];
      for (int t = 0; t < 5; t++) a += ste[b][t][s] * t1w[(l * 6 + q) * 5 + t];
      th[b][q][s] = a;
    }
    __syncthreads();
    for (int idx = tid; idx < 528; idx += 256) {
      int q = idx % 6, p = (idx / 6) % 11, b = idx / 66;
      float a = t2b[l * 11 + p];
      for (int s = 0; s < 10; s++) a += th[b][q][s] * t2w[(l * 11 + p) * 10 + s];
      coef[(l * 8 + b) * 66 + q * 11 + p] = fmaxf(a, 0.f);
    }
    __syncthreads();
  }
}

// ---------------- k2: start 1x1 conv ----------------
__global__ __launch_bounds__(256) void k2_start(const float* __restrict__ src,
                                                const float* __restrict__ w,
                                                const float* __restrict__ bia,
                                                float* __restrict__ x) {
  int idx = blockIdx.x * 256 + threadIdx.x;
  if (idx >= B_ * C_ * NT) return;
  int pos = idx % NT, r = idx / NT, c = r & 63, b = r >> 6;
  int n = pos / 12, t = pos - 12 * n;
  float s = src[(b * 12 + t) * N_ + n];
  x[idx] = s * w[c] + bia[c];
}

// ---------------- k3: fused basis recursion + x_st accumulation ----------------
// waves_per_eu(4,4): LDS (79KB) caps at 2 blocks/CU = 4 waves/EU; pin the
// register allocator to that occupancy (VGPR budget 128) so the temporal
// arrays registerize instead of spilling to scratch (R10: 293 MB WRITE_SIZE).
// Spatial norm fused into the A/B/C reduction: ||r-d1 l-d2 s||^2 =
// ||r||^2 - d1^2 - d2^2 (exact for unit l,s).
__global__ __launch_bounds__(512)
__attribute__((amdgpu_waves_per_eu(4, 4))) void k3_basis(
    const float* __restrict__ x, const float* __restrict__ LsT,
    const float* __restrict__ tp, const float* __restrict__ coef,
    float* __restrict__ xst) {
  __shared__ float sb[2][3940];        // 328 rows x 12 (rows 325..327 stay 0)
  __shared__ float scr[8][369][4];     // matmul partial-combine scratch
  __shared__ float sred[2][8][4];
  const int tid = threadIdx.x;
  const int bc = blockIdx.x;
  const float* cf = coef + (bc >> 6) * 66;
  const float* xs = x + (size_t)bc * NT;
  float* xo = xst + (size_t)bc * NT;

  // spatial mapping
  const int sq = tid / 3, tq = tid - 3 * sq;
  const int mq = sq / 41, rq = sq - 41 * mq;
  const bool actS = (sq < 164);
  const bool mq0 = actS && (mq == 0);
  const int n0 = rq * 8, t0 = tq * 4;
  const int mm0 = mq * 82;
  const int mm1 = (mq == 3) ? 325 : (mm0 + 82);
  const int e0 = n0 * 12 + t0;
  const int cid = rq * 3 + tq;         // combine index for mq0 threads

  // temporal layout
  const bool actT = (tid < N_);
  const int rowOff = tid * 12;

  float w[11];
#pragma unroll
  for (int k = 0; k < 11; k++) w[k] = tp[k * 12 + k + 1];

  float last[12], sec[12], acc[12], rr[12];
  int p = 0, m = 0, spc = 0;

  // zero sb pad rows (325..327 of both buffers)
  if (tid < 80) {
    int bsel = tid / 40, off = tid - 40 * bsel;
    sb[bsel][3900 + off] = 0.f;
  }

  // ---- m00 = unit(residual slice) (temporal layout) ----
  {
    float np = 0.f;
#pragma unroll
    for (int u = 0; u < 12; u++) rr[u] = 0.f;
    if (actT) {
      const float4 a = *(const float4*)(xs + rowOff);
      const float4 b4 = *(const float4*)(xs + rowOff + 4);
      const float4 c4 = *(const float4*)(xs + rowOff + 8);
      rr[0] = a.x; rr[1] = a.y; rr[2] = a.z; rr[3] = a.w;
      rr[4] = b4.x; rr[5] = b4.y; rr[6] = b4.z; rr[7] = b4.w;
      rr[8] = c4.x; rr[9] = c4.y; rr[10] = c4.z; rr[11] = c4.w;
#pragma unroll
      for (int u = 0; u < 12; u++) np += rr[u] * rr[u];
    }
    p ^= 1; redN(&np, 1, sred[p], tid);
    const float inv = 1.f / fmaxf(sqrtf(np), 1e-8f);
    const float c0 = cf[m]; m++;
#pragma unroll
    for (int u = 0; u < 12; u++) {
      last[u] = rr[u] * inv;
      acc[u] = c0 * last[u];
      sec[u] = 0.f;
    }
    if (actT) {
      float4 wv;
      wv.x = last[0]; wv.y = last[1]; wv.z = last[2]; wv.w = last[3];
      *(float4*)&sb[0][rowOff] = wv;
      wv.x = last[4]; wv.y = last[5]; wv.z = last[6]; wv.w = last[7];
      *(float4*)&sb[0][rowOff + 4] = wv;
      wv.x = last[8]; wv.y = last[9]; wv.z = last[10]; wv.w = last[11];
      *(float4*)&sb[0][rowOff + 8] = wv;
    }
    __syncthreads();
  }

  for (int i = 0; i <= 10; i++) {
    if (i > 0) {
      // ---------- spatial step: last_s = sb[spc], sec_s = sb[sps] ----------
      const int sps = 1 - spc;
      const bool hasSec = (i >= 2);
      float rt[8][4];
#pragma unroll
      for (int ii = 0; ii < 8; ii++)
#pragma unroll
        for (int j = 0; j < 4; j++) rt[ii][j] = 0.f;
      if (actS) {
        const float* lpc = LsT + n0;
        const float* sc = &sb[spc][t0];
#pragma unroll 2
        for (int mm = mm0; mm < mm1; mm++) {
          const float4 a0 = *(const float4*)(lpc + mm * LSP);
          const float4 a1 = *(const float4*)(lpc + mm * LSP + 4);
          const float4 mr = *(const float4*)(sc + mm * 12);
          rt[0][0] += a0.x * mr.x; rt[0][1] += a0.x * mr.y; rt[0][2] += a0.x * mr.z; rt[0][3] += a0.x * mr.w;
          rt[1][0] += a0.y * mr.x; rt[1][1] += a0.y * mr.y; rt[1][2] += a0.y * mr.z; rt[1][3] += a0.y * mr.w;
          rt[2][0] += a0.z * mr.x; rt[2][1] += a0.z * mr.y; rt[2][2] += a0.z * mr.z; rt[2][3] += a0.z * mr.w;
          rt[3][0] += a0.w * mr.x; rt[3][1] += a0.w * mr.y; rt[3][2] += a0.w * mr.z; rt[3][3] += a0.w * mr.w;
          rt[4][0] += a1.x * mr.x; rt[4][1] += a1.x * mr.y; rt[4][2] += a1.x * mr.z; rt[4][3] += a1.x * mr.w;
          rt[5][0] += a1.y * mr.x; rt[5][1] += a1.y * mr.y; rt[5][2] += a1.y * mr.z; rt[5][3] += a1.y * mr.w;
          rt[6][0] += a1.z * mr.x; rt[6][1] += a1.z * mr.y; rt[6][2] += a1.z * mr.z; rt[6][3] += a1.z * mr.w;
          rt[7][0] += a1.w * mr.x; rt[7][1] += a1.w * mr.y; rt[7][2] += a1.w * mr.z; rt[7][3] += a1.w * mr.w;
        }
      }
      // combine partials: mq>0 write, mq0 accumulate
      if (actS && mq > 0) {
        const int widx = (mq - 1) * 123 + cid;
#pragma unroll
        for (int ii = 0; ii < 8; ii++) {
          float4 wv;
          wv.x = rt[ii][0]; wv.y = rt[ii][1]; wv.z = rt[ii][2]; wv.w = rt[ii][3];
          *(float4*)&scr[ii][widx][0] = wv;
        }
      }
      __syncthreads();
      // A=<r,l>, B=<r,s>, C=<l,s>, R2=<r,r> in ONE reduction
      float v4[4] = {0.f, 0.f, 0.f, 0.f};
      if (mq0) {
#pragma unroll
        for (int kk = 0; kk < 3; kk++) {
          const int ridx = kk * 123 + cid;
#pragma unroll
          for (int ii = 0; ii < 8; ii++) {
            const float4 q = *(const float4*)&scr[ii][ridx][0];
            rt[ii][0] += q.x; rt[ii][1] += q.y; rt[ii][2] += q.z; rt[ii][3] += q.w;
          }
        }
#pragma unroll
        for (int ii = 0; ii < 8; ii++) {
          const float4 lq = *(const float4*)&sb[spc][e0 + ii * 12];
          v4[0] += rt[ii][0] * lq.x + rt[ii][1] * lq.y + rt[ii][2] * lq.z + rt[ii][3] * lq.w;
          v4[3] += rt[ii][0] * rt[ii][0] + rt[ii][1] * rt[ii][1] +
                   rt[ii][2] * rt[ii][2] + rt[ii][3] * rt[ii][3];
          if (hasSec) {
            const float4 sq4 = *(const float4*)&sb[sps][e0 + ii * 12];
            v4[1] += rt[ii][0] * sq4.x + rt[ii][1] * sq4.y + rt[ii][2] * sq4.z + rt[ii][3] * sq4.w;
            v4[2] += lq.x * sq4.x + lq.y * sq4.y + lq.z * sq4.z + lq.w * sq4.w;
          }
        }
      }
      p ^= 1; redN(v4, 4, sred[p], tid);
      const float d1 = v4[0];
      const float d2 = hasSec ? (v4[1] - d1 * v4[2]) : 0.f;
      const float np = fmaxf(v4[3] - d1 * d1 - d2 * d2, 0.f);
      const float inv = 1.f / fmaxf(sqrtf(np), 1e-8f);
      const float cs = cf[m]; m++;
      if (mq0) {
#pragma unroll
        for (int ii = 0; ii < 8; ii++) {
          const float4 lq = *(const float4*)&sb[spc][e0 + ii * 12];
          float sx = 0.f, sy = 0.f, sz = 0.f, sw = 0.f;
          if (hasSec) {
            const float4 sq4 = *(const float4*)&sb[sps][e0 + ii * 12];
            sx = sq4.x; sy = sq4.y; sz = sq4.z; sw = sq4.w;
          }
          float4 wv;
          wv.x = (rt[ii][0] - d1 * lq.x - d2 * sx) * inv;
          wv.y = (rt[ii][1] - d1 * lq.y - d2 * sy) * inv;
          wv.z = (rt[ii][2] - d1 * lq.z - d2 * sz) * inv;
          wv.w = (rt[ii][3] - d1 * lq.w - d2 * sw) * inv;
          *(float4*)&sb[sps][e0 + ii * 12] = wv;   // pad rows write 0
        }
      }
      spc = sps;
      __syncthreads();
      // temporal-layout init: load new M_i0 row; acc += c*row; sec <- 0
      if (actT) {
        const float4 a = *(const float4*)&sb[spc][rowOff];
        const float4 b4 = *(const float4*)&sb[spc][rowOff + 4];
        const float4 c4 = *(const float4*)&sb[spc][rowOff + 8];
        last[0] = a.x; last[1] = a.y; last[2] = a.z; last[3] = a.w;
        last[4] = b4.x; last[5] = b4.y; last[6] = b4.z; last[7] = b4.w;
        last[8] = c4.x; last[9] = c4.y; last[10] = c4.z; last[11] = c4.w;
#pragma unroll
        for (int u = 0; u < 12; u++) {
          acc[u] += cs * last[u];
          sec[u] = 0.f;
        }
      }
    }
    // ---------- temporal chain (5 steps), one fused reduction per step ------
    for (int j5 = 0; j5 < 5; j5++) {
      float v4[4] = {0.f, 0.f, 0.f, 0.f};
      if (actT) {
#pragma unroll
        for (int u = 0; u < 12; u++) {
          float r = 0.f;
          if (u > 0) r += last[u - 1] * w[u - 1];
          if (u < 11) r += last[u + 1] * w[u];
          rr[u] = r;
          v4[0] += r * last[u];
          v4[1] += r * sec[u];
          v4[2] += last[u] * sec[u];
          v4[3] += r * r;
        }
      }
      p ^= 1; redN(v4, 4, sred[p], tid);
      const float d1 = v4[0];
      const float d2 = v4[1] - d1 * v4[2];
      const float np = fmaxf(v4[3] - d1 * d1 - d2 * d2, 0.f);
      const float inv = 1.f / fmaxf(sqrtf(np), 1e-8f);
      const float c = cf[m]; m++;
      if (actT) {
#pragma unroll
        for (int u = 0; u < 12; u++) {
          const float v = (rr[u] - d1 * last[u] - d2 * sec[u]) * inv;
          sec[u] = last[u];
          last[u] = v;
          acc[u] += c * v;
        }
      }
    }
  }
  if (actT) {
    float4 wv;
    wv.x = acc[0]; wv.y = acc[1]; wv.z = acc[2]; wv.w = acc[3];
    *(float4*)(xo + rowOff) = wv;
    wv.x = acc[4]; wv.y = acc[5]; wv.z = acc[6]; wv.w = acc[7];
    *(float4*)(xo + rowOff + 4) = wv;
    wv.x = acc[8]; wv.y = acc[9]; wv.z = acc[10]; wv.w = acc[11];
    *(float4*)(xo + rowOff + 8) = wv;
  }
}

// ---------------- k45: fused layer body, one block per (b,n) ----------------
__global__ __launch_bounds__(256) void k45_layer(
    float* __restrict__ x, const float* __restrict__ xst,
    const float* __restrict__ stw, const float* __restrict__ stb,
    const float* __restrict__ stg, const float* __restrict__ stbb,
    const float* __restrict__ stm, const float* __restrict__ stv,
    const float* __restrict__ p1w, const float* __restrict__ p1b,
    const float* __restrict__ p2w, const float* __restrict__ p2b,
    const float* __restrict__ p3w, const float* __restrict__ p3b,
    const float* __restrict__ pcw, const float* __restrict__ pcb,
    const float* __restrict__ pbg, const float* __restrict__ pbb,
    const float* __restrict__ pbm, const float* __restrict__ pbv,
    const float* __restrict__ bng, const float* __restrict__ bnb,
    const float* __restrict__ bnm, const float* __restrict__ bnv,
    const float* __restrict__ skw, const float* __restrict__ skb,
    float* __restrict__ skipb, int accum) {
  __shared__ float xr[64][12];
  __shared__ float xq[64][12];
  __shared__ float hd[64][12];
  __shared__ float g1s[64][12];
  __shared__ float g2s[64][4];
  __shared__ float g3s[64][2];
  __shared__ float fu[64][12];
  const int tid = threadIdx.x;
  const int bid = blockIdx.x;
  const int b = bid / N_, n = bid - N_ * b;
  const size_t base = ((size_t)b * 64) * NT + n * 12;
  if (tid < 192) {
    int c = tid / 3, ch = tid - 3 * (tid / 3);
    *(float4*)&xr[c][ch * 4] = *(const float4*)(x + base + (size_t)c * NT + ch * 4);
    *(float4*)&xq[c][ch * 4] = *(const float4*)(xst + base + (size_t)c * NT + ch * 4);
  }
  __syncthreads();
  if (tid < 192) {
    int oq = tid / 12, t = tid - 12 * (tid / 12);
    float a0 = 0, a1 = 0, a2 = 0, a3 = 0;
    const float* w0 = stw + (4 * oq) * 128;
    for (int i = 0; i < 64; i++) {
      float h = xr[i][t];
      a0 += h * w0[i]; a1 += h * w0[128 + i];
      a2 += h * w0[256 + i]; a3 += h * w0[384 + i];
    }
    for (int i = 0; i < 64; i++) {
      float h = xq[i][t];
      a0 += h * w0[64 + i]; a1 += h * w0[192 + i];
      a2 += h * w0[320 + i]; a3 += h * w0[448 + i];
    }
    float av[4] = {a0, a1, a2, a3};
#pragma unroll
    for (int k = 0; k < 4; k++) {
      int o = 4 * oq + k;
      float y = av[k] + stb[o];
      float sc = stg[o] / sqrtf(stv[o] + 1e-5f);
      hd[o][t] = (y - stm[o]) * sc + stbb[o];
    }
  }
  __syncthreads();
  if (tid < 192) {
    int oq = tid / 12, t = tid - 12 * (tid / 12);
    float s0 = 0, s1 = 0, s2 = 0, s3 = 0, u0 = 0, u1 = 0, u2 = 0, u3 = 0;
    const float* wsr = p1w + (4 * oq) * 64;
    for (int i = 0; i < 64; i++) {
      float h = hd[i][t];
      s0 += h * wsr[i]; s1 += h * wsr[64 + i];
      s2 += h * wsr[128 + i]; s3 += h * wsr[192 + i];
      u0 += h * wsr[4096 + i]; u1 += h * wsr[4096 + 64 + i];
      u2 += h * wsr[4096 + 128 + i]; u3 += h * wsr[4096 + 192 + i];
    }
    float sv[4] = {s0, s1, s2, s3}, uv[4] = {u0, u1, u2, u3};
#pragma unroll
    for (int k = 0; k < 4; k++) {
      int o = 4 * oq + k;
      g1s[o][t] = sigm(sv[k] + p1b[o]) * tanhf(uv[k] + p1b[o + 64]);
    }
  }
  if (tid < 128) {
    int oq = tid / 4, q = tid & 3;
    float s0 = 0, s1 = 0, u0 = 0, u1 = 0;
    const float* wsr = p2w + (2 * oq) * 192;
    for (int i = 0; i < 64; i++)
#pragma unroll
      for (int kk = 0; kk < 3; kk++) {
        float h = hd[i][3 * q + kk];
        s0 += h * wsr[i * 3 + kk]; s1 += h * wsr[192 + i * 3 + kk];
        u0 += h * wsr[12288 + i * 3 + kk]; u1 += h * wsr[12288 + 192 + i * 3 + kk];
      }
    int o = 2 * oq;
    g2s[o][q] = sigm(s0 + p2b[o]) * tanhf(u0 + p2b[o + 64]);
    g2s[o + 1][q] = sigm(s1 + p2b[o + 1]) * tanhf(u1 + p2b[o + 65]);
  } else if (tid < 192) {
    int r = tid - 128;
    int oq = r / 2, q = r & 1;
    float s0 = 0, s1 = 0, u0 = 0, u1 = 0;
    const float* wsr = p3w + (2 * oq) * 384;
    for (int i = 0; i < 64; i++)
#pragma unroll
      for (int kk = 0; kk < 6; kk++) {
        float h = hd[i][6 * q + kk];
        s0 += h * wsr[i * 6 + kk]; s1 += h * wsr[384 + i * 6 + kk];
        u0 += h * wsr[24576 + i * 6 + kk]; u1 += h * wsr[24576 + 384 + i * 6 + kk];
      }
    int o = 2 * oq;
    g3s[o][q] = sigm(s0 + p3b[o]) * tanhf(u0 + p3b[o + 64]);
    g3s[o + 1][q] = sigm(s1 + p3b[o + 1]) * tanhf(u1 + p3b[o + 65]);
  }
  __syncthreads();
  if (tid < 192) {
    int oq = tid / 12, t = tid - 12 * (tid / 12);
    float a0 = 0, a1 = 0, a2 = 0, a3 = 0;
    const float* w0 = pcw + (4 * oq) * 192;
    for (int c = 0; c < 64; c++) {
      float v = g1s[c][t];
      a0 += v * w0[c]; a1 += v * w0[192 + c];
      a2 += v * w0[384 + c]; a3 += v * w0[576 + c];
    }
    float c4 = fminf(fmaxf((t - 1) * (1.f / 3.f), 0.f), 3.f);
    int q0 = (int)c4;
    float f4 = c4 - (float)q0;
    int q1 = min(q0 + 1, 3);
    for (int c = 0; c < 64; c++) {
      float v = (1.f - f4) * g2s[c][q0] + f4 * g2s[c][q1];
      a0 += v * w0[64 + c]; a1 += v * w0[192 + 64 + c];
      a2 += v * w0[384 + 64 + c]; a3 += v * w0[576 + 64 + c];
    }
    float f2 = fminf(fmaxf((2 * t - 5) * (1.f / 12.f), 0.f), 1.f);
    for (int c = 0; c < 64; c++) {
      float v = (1.f - f2) * g3s[c][0] + f2 * g3s[c][1];
      a0 += v * w0[128 + c]; a1 += v * w0[192 + 128 + c];
      a2 += v * w0[384 + 128 + c]; a3 += v * w0[576 + 128 + c];
    }
    float av[4] = {a0, a1, a2, a3};
#pragma unroll
    for (int k = 0; k < 4; k++) {
      int o = 4 * oq + k;
      float y = av[k] + pcb[o];
      float s1 = pbg[o] / sqrtf(pbv[o] + 1e-5f);
      float fv = (y - pbm[o]) * s1 + pbb[o];
      fu[o][t] = fv;
      float s2 = bng[o] / sqrtf(bnv[o] + 1e-5f);
      xr[o][t] = (fv + xr[o][t] - bnm[o]) * s2 + bnb[o];
    }
  }
  __syncthreads();
  if (tid < 192) {
    int c = tid / 3, ch = tid - 3 * (tid / 3);
    *(float4*)(x + base + (size_t)c * NT + ch * 4) = *(float4*)&xr[c][ch * 4];
  }
  if (tid < 128) {
    float a = skb[tid];
    const float* wr = skw + tid * 64;
    for (int c = 0; c < 64; c++) a += fu[c][11] * wr[c];
    size_t o = ((size_t)b * 128 + tid) * N_ + n;
    skipb[o] = accum ? (skipb[o] + a) : a;
  }
}

// ---------------- k6: end MLP per (b,n) — fp32 output ----------------
__global__ __launch_bounds__(256) void k6_end(const float* __restrict__ skip,
                                              const float* __restrict__ w1,
                                              const float* __restrict__ b1,
                                              const float* __restrict__ w2,
                                              const float* __restrict__ b2,
                                              float* __restrict__ out) {
  __shared__ float sk[128];
  __shared__ float h[256];
  const int blk = blockIdx.x;
  const int b = blk / N_;
  const int n = blk - N_ * b;
  const int tid = threadIdx.x;
  if (tid < 128) sk[tid] = fmaxf(skip[((size_t)b * 128 + tid) * N_ + n], 0.f);
  __syncthreads();
  {
    float a = b1[tid];
    for (int s = 0; s < 128; s++) a += w1[tid * 128 + s] * sk[s];
    h[tid] = fmaxf(a, 0.f);
  }
  __syncthreads();
  if (tid < 12) {
    float a = b2[tid];
    for (int e = 0; e < 256; e++) a += w2[tid * 256 + e] * h[e];
    out[((size_t)b * 12 + tid) * N_ + n] = a;
  }
}

// ---------------- host ----------------
extern "C" void kernel_launch(void* const* d_in, const int* in_sizes, int n_in,
                              void* d_out, int out_size, void* d_ws, size_t ws_size,
                              hipStream_t stream) {
  (void)in_sizes; (void)n_in;
  if (ws_size < (size_t)44 * 1024 * 1024) {
    k_sentinel<<<(out_size + 255) / 256, 256, 0, stream>>>((float*)d_out, out_size);
    return;
  }
  const float* src = (const float*)d_in[0];
  const int* TE = (const int*)d_in[1];
  const float* sp = (const float*)d_in[2];
  const float* tp = (const float*)d_in[3];
  const float* SE = (const float*)d_in[4];
  const float* tmlp1_w = (const float*)d_in[5];
  const float* tmlp1_b = (const float*)d_in[6];
  const float* tmlp2_w = (const float*)d_in[7];
  const float* tmlp2_b = (const float*)d_in[8];
  const float* smlp1_w = (const float*)d_in[9];
  const float* smlp1_b = (const float*)d_in[10];
  const float* smlp2_w = (const float*)d_in[11];
  const float* smlp2_b = (const float*)d_in[12];
  const float* start_w = (const float*)d_in[13];
  const float* start_b = (const float*)d_in[14];
  const float* th1w = (const float*)d_in[15];
  const float* th1b = (const float*)d_in[16];
  const float* th2w = (const float*)d_in[17];
  const float* th2b = (const float*)d_in[18];
  const float* stw = (const float*)d_in[19];
  const float* stb = (const float*)d_in[20];
  const float* stg = (const float*)d_in[21];
  const float* stbb = (const float*)d_in[22];
  const float* stm = (const float*)d_in[23];
  const float* stv = (const float*)d_in[24];
  const float* p1w = (const float*)d_in[25];
  const float* p1b = (const float*)d_in[26];
  const float* p2w = (const float*)d_in[27];
  const float* p2b = (const float*)d_in[28];
  const float* p3w = (const float*)d_in[29];
  const float* p3b = (const float*)d_in[30];
  const float* pcw = (const float*)d_in[31];
  const float* pcb = (const float*)d_in[32];
  const float* pbg = (const float*)d_in[33];
  const float* pbb = (const float*)d_in[34];
  const float* pbm = (const float*)d_in[35];
  const float* pbv = (const float*)d_in[36];
  const float* skw = (const float*)d_in[37];
  const float* skb = (const float*)d_in[38];
  const float* bng = (const float*)d_in[39];
  const float* bnb = (const float*)d_in[40];
  const float* bnm = (const float*)d_in[41];
  const float* bnv = (const float*)d_in[42];
  const float* e1w = (const float*)d_in[43];
  const float* e1b = (const float*)d_in[44];
  const float* e2w = (const float*)d_in[45];
  const float* e2b = (const float*)d_in[46];

  float* ws = (float*)d_ws;
  float* coef = ws + 0;              // 2*8*66
  float* LsT  = ws + 8192;           // 325*328
  float* x    = ws + 4194304;        // [B,64,N,T]
  float* xst  = ws + 6291456;        // x_st
  float* skipb= ws + 10485760;       // [B,128,N]

  k0_convert<<<(N_ * LSP + 255) / 256, 256, 0, stream>>>(sp, LsT);
  k1_embed<<<1, 256, 0, stream>>>(TE, SE, tmlp1_w, tmlp1_b, tmlp2_w, tmlp2_b,
                                  smlp1_w, smlp1_b, smlp2_w, smlp2_b,
                                  th1w, th1b, th2w, th2b, coef);
  k2_start<<<(B_ * C_ * NT + 255) / 256, 256, 0, stream>>>(src, start_w, start_b, x);

  for (int l = 0; l < 2; l++) {
    k3_basis<<<512, 512, 0, stream>>>(x, LsT, tp, coef + l * 528, xst);
    k45_layer<<<B_ * N_, 256, 0, stream>>>(
        x, xst,
        stw + l * 8192, stb + l * 64, stg + l * 64, stbb + l * 64,
        stm + l * 64, stv + l * 64,
        p1w + l * 8192, p1b + l * 128,
        p2w + l * 24576, p2b + l * 128,
        p3w + l * 49152, p3b + l * 128,
        pcw + l * 12288, pcb + l * 64,
        pbg + l * 64, pbb + l * 64, pbm + l * 64, pbv + l * 64,
        bng + l * 64, bnb + l * 64, bnm + l * 64, bnv + l * 64,
        skw + l * 8192, skb + l * 128,
        skipb, l);
  }
  k6_end<<<B_ * N_, 256, 0, stream>>>(skipb, e1w, e1b, e2w, e2b, (float*)d_out);
}

// Round 12
// 1315.578 us; speedup vs baseline: 1.2892x; 1.1203x over previous
//
#include <hip/hip_runtime.h>
#include <hip/hip_bf16.h>
#include <math.h>

// ---------------- problem constants ----------------
#define B_   8
#define T_   12
#define N_   325
#define C_   64
#define NT   3900     // N_*T_
#define LSP  328      // padded row stride of transposed sp matrix

__device__ __forceinline__ float sigm(float x) { return 1.f / (1.f + expf(-x)); }

// 512-thread (8-wave) multi-value reduction; ONE barrier (caller ping-pongs redb)
__device__ __forceinline__ void redN(float* v, int nv, float (*redb)[4], int tid) {
#pragma unroll
  for (int off = 1; off < 64; off <<= 1) {
    for (int i = 0; i < nv; i++) v[i] += __shfl_xor(v[i], off, 64);
  }
  if ((tid & 63) == 0) {
    for (int i = 0; i < nv; i++) redb[tid >> 6][i] = v[i];
  }
  __syncthreads();
  for (int i = 0; i < nv; i++) {
    float s = 0.f;
#pragma unroll
    for (int w = 0; w < 8; w++) s += redb[w][i];
    v[i] = s;
  }
}

// ---------------- sentinel (ws too small diagnostic) ----------------
__global__ __launch_bounds__(256) void k_sentinel(float* out, int n) {
  int i = blockIdx.x * 256 + threadIdx.x;
  if (i < n) out[i] = 7.0f;
}

// ---------------- k0: transpose sp (padded) ----------------
__global__ __launch_bounds__(256) void k0_convert(const float* __restrict__ sp,
                                                  float* __restrict__ LsT) {
  int idx = blockIdx.x * 256 + threadIdx.x;
  if (idx < N_ * LSP) {
    int m = idx / LSP, n = idx - m * LSP;
    LsT[idx] = (n < N_) ? sp[n * N_ + m] : 0.f;   // LsT[m][n] = Ls[n][m]
  }
}

// ---------------- k1: embeddings + theta coefficients ----------------
__global__ __launch_bounds__(256) void k1_embed(
    const int* __restrict__ TE, const float* __restrict__ SE,
    const float* __restrict__ w1, const float* __restrict__ b1,
    const float* __restrict__ w2, const float* __restrict__ b2,
    const float* __restrict__ sw1, const float* __restrict__ sb1,
    const float* __restrict__ sw2, const float* __restrict__ sb2,
    const float* __restrict__ t1w, const float* __restrict__ t1b,
    const float* __restrict__ t2w, const float* __restrict__ t2b,
    float* __restrict__ coef) {
  __shared__ float te2[8][10][12];
  __shared__ float ste[8][5][10];
  __shared__ float se1[5][10];
  __shared__ float se2[5][10];
  __shared__ float th[8][6][10];
  __shared__ int te64;
  const int tid = threadIdx.x;
  if (tid == 0) {
    int nz = 0;
    for (int k2 = 0; k2 < 96; k2++) nz += (TE[2 * k2 + 1] != 0) ? 1 : 0;
    te64 = (nz == 0) ? 1 : 0;
  }
  __syncthreads();
  for (int idx = tid; idx < 960; idx += 256) {
    int t = idx % 12, o = (idx / 12) % 10, b = idx / 120;
    int q = (b * 12 + t) * 2;
    int d = (te64 ? TE[2 * q] : TE[q]) % 7;
    int h = (te64 ? TE[2 * q + 2] : TE[q + 1]) % 288;
    float v = w1[o * 295 + d] + w1[o * 295 + 7 + h] + b1[o];
    te2[b][o][t] = fmaxf(v, 0.f);
  }
  __syncthreads();
  for (int idx = tid; idx < 400; idx += 256) {
    int s = idx % 10, o = (idx / 10) % 5, b = idx / 50;
    float a = b2[o];
    for (int t = 0; t < 12; t++) a += te2[b][s][t] * w2[o * 12 + t];
    ste[b][o][s] = fmaxf(a, 0.f);
  }
  if (tid < 50) {
    int o = tid / 10, j = tid % 10;
    float a = sb1[o];
    for (int n = 0; n < N_; n++) a += sw1[o * N_ + n] * SE[n * 10 + j];
    se1[o][j] = fmaxf(a, 0.f);
  }
  __syncthreads();
  if (tid < 50) {
    int t = tid / 10, s = tid % 10;
    float a = sb2[s];
    for (int j = 0; j < 10; j++) a += sw2[s * 10 + j] * se1[t][j];
    se2[t][s] = fmaxf(a, 0.f);
  }
  __syncthreads();
  for (int idx = tid; idx < 400; idx += 256) {
    int s = idx % 10, o = (idx / 10) % 5, b = idx / 50;
    ste[b][o][s] = fmaxf(se2[o][s] + ste[b][o][s], 0.f);
  }
  __syncthreads();
  for (int l = 0; l < 2; l++) {
    for (int idx = tid; idx < 480; idx += 256) {
      int s = idx % 10, q = (idx / 10) % 6, b = idx / 60;
      float a = t1b[l * 6 + q];
      for (int t = 0; t < 5; t++) a += ste[b][t][s] * t1w[(l * 6 + q) * 5 + t];
      th[b][q][s] = a;
    }
    __syncthreads();
    for (int idx = tid; idx < 528; idx += 256) {
      int q = idx % 6, p = (idx / 6) % 11, b = idx / 66;
      float a = t2b[l * 11 + p];
      for (int s = 0; s < 10; s++) a += th[b][q][s] * t2w[(l * 11 + p) * 10 + s];
      coef[(l * 8 + b) * 66 + q * 11 + p] = fmaxf(a, 0.f);
    }
    __syncthreads();
  }
}

// ---------------- k2: start 1x1 conv ----------------
__global__ __launch_bounds__(256) void k2_start(const float* __restrict__ src,
                                                const float* __restrict__ w,
                                                const float* __restrict__ bia,
                                                float* __restrict__ x) {
  int idx = blockIdx.x * 256 + threadIdx.x;
  if (idx >= B_ * C_ * NT) return;
  int pos = idx % NT, r = idx / NT, c = r & 63, b = r >> 6;
  int n = pos / 12, t = pos - 12 * n;
  float s = src[(b * 12 + t) * N_ + n];
  x[idx] = s * w[c] + bia[c];
}

// ---------------- k3: fused basis recursion + x_st accumulation ----------------
// Designed to fit the 64-VGPR budget (R10/R11: allocator pins 8 waves/EU and
// spilled 250-300 MB to scratch). Spatial: 4-row x 4-col tiles, mm-split 2
// (82 rq x 3 tq x 2 mq = 492 threads; ~45 live regs). Temporal: register
// tridiagonal chain with r RECOMPUTED in the update pass (drops rr[12]).
__global__ __launch_bounds__(512) void k3_basis(
    const float* __restrict__ x, const float* __restrict__ LsT,
    const float* __restrict__ tp, const float* __restrict__ coef,
    float* __restrict__ xst) {
  __shared__ float sb[2][3940];        // 328 rows x 12 (rows 325..327 stay 0)
  __shared__ float scr[4][246][4];     // matmul partial-combine scratch (1 lvl)
  __shared__ float sred[2][8][4];
  const int tid = threadIdx.x;
  const int bc = blockIdx.x;
  const float* cf = coef + (bc >> 6) * 66;
  const float* xs = x + (size_t)bc * NT;
  float* xo = xst + (size_t)bc * NT;

  // spatial mapping: sq = (mq, rq); 4 rows x 4 cols per thread, mm halves
  const int sq = tid / 3, tq = tid - 3 * sq;
  const int mq = sq / 82, rq = sq - 82 * mq;
  const bool actS = (sq < 164);
  const bool mq0 = actS && (mq == 0);
  const int n0 = rq * 4, t0 = tq * 4;
  const int mm0 = mq ? 163 : 0;
  const int mm1 = mq ? 325 : 163;
  const int e0 = n0 * 12 + t0;
  const int cid = rq * 3 + tq;         // 0..245

  // temporal layout: one row per thread (325 active)
  const bool actT = (tid < N_);
  const int rowOff = tid * 12;

  float w[11];
#pragma unroll
  for (int k = 0; k < 11; k++) w[k] = tp[k * 12 + k + 1];

  float last[12], sec[12], acc[12];
  int p = 0, m = 0, spc = 0;

  // zero sb pad rows (325..327 of both buffers)
  if (tid < 80) {
    int bsel = tid / 40, off = tid - 40 * bsel;
    sb[bsel][3900 + off] = 0.f;
  }

  // ---- m00 = unit(residual slice) (temporal layout) ----
  {
    float np = 0.f;
#pragma unroll
    for (int u = 0; u < 12; u++) last[u] = 0.f;
    if (actT) {
      const float4 a = *(const float4*)(xs + rowOff);
      const float4 b4 = *(const float4*)(xs + rowOff + 4);
      const float4 c4 = *(const float4*)(xs + rowOff + 8);
      last[0] = a.x; last[1] = a.y; last[2] = a.z; last[3] = a.w;
      last[4] = b4.x; last[5] = b4.y; last[6] = b4.z; last[7] = b4.w;
      last[8] = c4.x; last[9] = c4.y; last[10] = c4.z; last[11] = c4.w;
#pragma unroll
      for (int u = 0; u < 12; u++) np += last[u] * last[u];
    }
    p ^= 1; redN(&np, 1, sred[p], tid);
    const float inv = 1.f / fmaxf(sqrtf(np), 1e-8f);
    const float c0 = cf[m]; m++;
#pragma unroll
    for (int u = 0; u < 12; u++) {
      last[u] *= inv;
      acc[u] = c0 * last[u];
      sec[u] = 0.f;
    }
    if (actT) {
      float4 wv;
      wv.x = last[0]; wv.y = last[1]; wv.z = last[2]; wv.w = last[3];
      *(float4*)&sb[0][rowOff] = wv;
      wv.x = last[4]; wv.y = last[5]; wv.z = last[6]; wv.w = last[7];
      *(float4*)&sb[0][rowOff + 4] = wv;
      wv.x = last[8]; wv.y = last[9]; wv.z = last[10]; wv.w = last[11];
      *(float4*)&sb[0][rowOff + 8] = wv;
    }
    __syncthreads();
  }

  for (int i = 0; i <= 10; i++) {
    if (i > 0) {
      // ---------- spatial step: last_s = sb[spc], sec_s = sb[sps] ----------
      const int sps = 1 - spc;
      const bool hasSec = (i >= 2);
      float rt[4][4];
#pragma unroll
      for (int ii = 0; ii < 4; ii++)
#pragma unroll
        for (int j = 0; j < 4; j++) rt[ii][j] = 0.f;
      if (actS) {
        const float* lpc = LsT + n0;
        const float* sc = &sb[spc][t0];
#pragma unroll 2
        for (int mm = mm0; mm < mm1; mm++) {
          const float4 a0 = *(const float4*)(lpc + mm * LSP);  // pad cols -> 0
          const float4 mr = *(const float4*)(sc + mm * 12);
          rt[0][0] += a0.x * mr.x; rt[0][1] += a0.x * mr.y; rt[0][2] += a0.x * mr.z; rt[0][3] += a0.x * mr.w;
          rt[1][0] += a0.y * mr.x; rt[1][1] += a0.y * mr.y; rt[1][2] += a0.y * mr.z; rt[1][3] += a0.y * mr.w;
          rt[2][0] += a0.z * mr.x; rt[2][1] += a0.z * mr.y; rt[2][2] += a0.z * mr.z; rt[2][3] += a0.z * mr.w;
          rt[3][0] += a0.w * mr.x; rt[3][1] += a0.w * mr.y; rt[3][2] += a0.w * mr.z; rt[3][3] += a0.w * mr.w;
        }
      }
      // combine partials: mq=1 writes, mq=0 accumulates
      if (actS && mq == 1) {
#pragma unroll
        for (int ii = 0; ii < 4; ii++) {
          float4 wv;
          wv.x = rt[ii][0]; wv.y = rt[ii][1]; wv.z = rt[ii][2]; wv.w = rt[ii][3];
          *(float4*)&scr[ii][cid][0] = wv;
        }
      }
      __syncthreads();
      // A=<r,l>, B=<r,s>, C=<l,s>, R2=<r,r> in ONE reduction
      float v4[4] = {0.f, 0.f, 0.f, 0.f};
      if (mq0) {
#pragma unroll
        for (int ii = 0; ii < 4; ii++) {
          const float4 q = *(const float4*)&scr[ii][cid][0];
          rt[ii][0] += q.x; rt[ii][1] += q.y; rt[ii][2] += q.z; rt[ii][3] += q.w;
        }
#pragma unroll
        for (int ii = 0; ii < 4; ii++) {
          const float4 lq = *(const float4*)&sb[spc][e0 + ii * 12];
          v4[0] += rt[ii][0] * lq.x + rt[ii][1] * lq.y + rt[ii][2] * lq.z + rt[ii][3] * lq.w;
          v4[3] += rt[ii][0] * rt[ii][0] + rt[ii][1] * rt[ii][1] +
                   rt[ii][2] * rt[ii][2] + rt[ii][3] * rt[ii][3];
          if (hasSec) {
            const float4 sq4 = *(const float4*)&sb[sps][e0 + ii * 12];
            v4[1] += rt[ii][0] * sq4.x + rt[ii][1] * sq4.y + rt[ii][2] * sq4.z + rt[ii][3] * sq4.w;
            v4[2] += lq.x * sq4.x + lq.y * sq4.y + lq.z * sq4.z + lq.w * sq4.w;
          }
        }
      }
      p ^= 1; redN(v4, 4, sred[p], tid);
      const float d1 = v4[0];
      const float d2 = hasSec ? (v4[1] - d1 * v4[2]) : 0.f;
      const float np = fmaxf(v4[3] - d1 * d1 - d2 * d2, 0.f);
      const float inv = 1.f / fmaxf(sqrtf(np), 1e-8f);
      const float cs = cf[m]; m++;
      if (mq0) {
#pragma unroll
        for (int ii = 0; ii < 4; ii++) {
          const float4 lq = *(const float4*)&sb[spc][e0 + ii * 12];
          float sx = 0.f, sy = 0.f, sz = 0.f, sw = 0.f;
          if (hasSec) {
            const float4 sq4 = *(const float4*)&sb[sps][e0 + ii * 12];
            sx = sq4.x; sy = sq4.y; sz = sq4.z; sw = sq4.w;
          }
          float4 wv;
          wv.x = (rt[ii][0] - d1 * lq.x - d2 * sx) * inv;
          wv.y = (rt[ii][1] - d1 * lq.y - d2 * sy) * inv;
          wv.z = (rt[ii][2] - d1 * lq.z - d2 * sz) * inv;
          wv.w = (rt[ii][3] - d1 * lq.w - d2 * sw) * inv;
          *(float4*)&sb[sps][e0 + ii * 12] = wv;   // pad rows write 0
        }
      }
      spc = sps;
      __syncthreads();
      // temporal-layout init: load new M_i0 row; acc += c*row; sec <- 0
      if (actT) {
        const float4 a = *(const float4*)&sb[spc][rowOff];
        const float4 b4 = *(const float4*)&sb[spc][rowOff + 4];
        const float4 c4 = *(const float4*)&sb[spc][rowOff + 8];
        last[0] = a.x; last[1] = a.y; last[2] = a.z; last[3] = a.w;
        last[4] = b4.x; last[5] = b4.y; last[6] = b4.z; last[7] = b4.w;
        last[8] = c4.x; last[9] = c4.y; last[10] = c4.z; last[11] = c4.w;
#pragma unroll
        for (int u = 0; u < 12; u++) {
          acc[u] += cs * last[u];
          sec[u] = 0.f;
        }
      }
    }
    // ---------- temporal chain (5 steps); r recomputed in update pass ------
    for (int j5 = 0; j5 < 5; j5++) {
      float v4[4] = {0.f, 0.f, 0.f, 0.f};
      if (actT) {
#pragma unroll
        for (int u = 0; u < 12; u++) {
          float r = 0.f;
          if (u > 0) r += last[u - 1] * w[u - 1];
          if (u < 11) r += last[u + 1] * w[u];
          v4[0] += r * last[u];
          v4[1] += r * sec[u];
          v4[2] += last[u] * sec[u];
          v4[3] += r * r;
        }
      }
      p ^= 1; redN(v4, 4, sred[p], tid);
      const float d1 = v4[0];
      const float d2 = v4[1] - d1 * v4[2];
      const float np = fmaxf(v4[3] - d1 * d1 - d2 * d2, 0.f);
      const float inv = 1.f / fmaxf(sqrtf(np), 1e-8f);
      const float c = cf[m]; m++;
      if (actT) {
        float pm1 = 0.f;
#pragma unroll
        for (int u = 0; u < 12; u++) {
          const float tmp = last[u];
          float r = 0.f;
          if (u > 0) r += pm1 * w[u - 1];
          if (u < 11) r += last[u + 1] * w[u];
          const float v = (r - d1 * tmp - d2 * sec[u]) * inv;
          acc[u] += c * v;
          sec[u] = tmp;
          last[u] = v;
          pm1 = tmp;
        }
      }
    }
  }
  if (actT) {
    float4 wv;
    wv.x = acc[0]; wv.y = acc[1]; wv.z = acc[2]; wv.w = acc[3];
    *(float4*)(xo + rowOff) = wv;
    wv.x = acc[4]; wv.y = acc[5]; wv.z = acc[6]; wv.w = acc[7];
    *(float4*)(xo + rowOff + 4) = wv;
    wv.x = acc[8]; wv.y = acc[9]; wv.z = acc[10]; wv.w = acc[11];
    *(float4*)(xo + rowOff + 8) = wv;
  }
}

// ---------------- k45: fused layer body, one block per (b,n) ----------------
__global__ __launch_bounds__(256) void k45_layer(
    float* __restrict__ x, const float* __restrict__ xst,
    const float* __restrict__ stw, const float* __restrict__ stb,
    const float* __restrict__ stg, const float* __restrict__ stbb,
    const float* __restrict__ stm, const float* __restrict__ stv,
    const float* __restrict__ p1w, const float* __restrict__ p1b,
    const float* __restrict__ p2w, const float* __restrict__ p2b,
    const float* __restrict__ p3w, const float* __restrict__ p3b,
    const float* __restrict__ pcw, const float* __restrict__ pcb,
    const float* __restrict__ pbg, const float* __restrict__ pbb,
    const float* __restrict__ pbm, const float* __restrict__ pbv,
    const float* __restrict__ bng, const float* __restrict__ bnb,
    const float* __restrict__ bnm, const float* __restrict__ bnv,
    const float* __restrict__ skw, const float* __restrict__ skb,
    float* __restrict__ skipb, int accum) {
  __shared__ float xr[64][12];
  __shared__ float xq[64][12];
  __shared__ float hd[64][12];
  __shared__ float g1s[64][12];
  __shared__ float g2s[64][4];
  __shared__ float g3s[64][2];
  __shared__ float fu[64][12];
  const int tid = threadIdx.x;
  const int bid = blockIdx.x;
  const int b = bid / N_, n = bid - N_ * b;
  const size_t base = ((size_t)b * 64) * NT + n * 12;
  if (tid < 192) {
    int c = tid / 3, ch = tid - 3 * (tid / 3);
    *(float4*)&xr[c][ch * 4] = *(const float4*)(x + base + (size_t)c * NT + ch * 4);
    *(float4*)&xq[c][ch * 4] = *(const float4*)(xst + base + (size_t)c * NT + ch * 4);
  }
  __syncthreads();
  if (tid < 192) {
    int oq = tid / 12, t = tid - 12 * (tid / 12);
    float a0 = 0, a1 = 0, a2 = 0, a3 = 0;
    const float* w0 = stw + (4 * oq) * 128;
    for (int i = 0; i < 64; i++) {
      float h = xr[i][t];
      a0 += h * w0[i]; a1 += h * w0[128 + i];
      a2 += h * w0[256 + i]; a3 += h * w0[384 + i];
    }
    for (int i = 0; i < 64; i++) {
      float h = xq[i][t];
      a0 += h * w0[64 + i]; a1 += h * w0[192 + i];
      a2 += h * w0[320 + i]; a3 += h * w0[448 + i];
    }
    float av[4] = {a0, a1, a2, a3};
#pragma unroll
    for (int k = 0; k < 4; k++) {
      int o = 4 * oq + k;
      float y = av[k] + stb[o];
      float sc = stg[o] / sqrtf(stv[o] + 1e-5f);
      hd[o][t] = (y - stm[o]) * sc + stbb[o];
    }
  }
  __syncthreads();
  if (tid < 192) {
    int oq = tid / 12, t = tid - 12 * (tid / 12);
    float s0 = 0, s1 = 0, s2 = 0, s3 = 0, u0 = 0, u1 = 0, u2 = 0, u3 = 0;
    const float* wsr = p1w + (4 * oq) * 64;
    for (int i = 0; i < 64; i++) {
      float h = hd[i][t];
      s0 += h * wsr[i]; s1 += h * wsr[64 + i];
      s2 += h * wsr[128 + i]; s3 += h * wsr[192 + i];
      u0 += h * wsr[4096 + i]; u1 += h * wsr[4096 + 64 + i];
      u2 += h * wsr[4096 + 128 + i]; u3 += h * wsr[4096 + 192 + i];
    }
    float sv[4] = {s0, s1, s2, s3}, uv[4] = {u0, u1, u2, u3};
#pragma unroll
    for (int k = 0; k < 4; k++) {
      int o = 4 * oq + k;
      g1s[o][t] = sigm(sv[k] + p1b[o]) * tanhf(uv[k] + p1b[o + 64]);
    }
  }
  if (tid < 128) {
    int oq = tid / 4, q = tid & 3;
    float s0 = 0, s1 = 0, u0 = 0, u1 = 0;
    const float* wsr = p2w + (2 * oq) * 192;
    for (int i = 0; i < 64; i++)
#pragma unroll
      for (int kk = 0; kk < 3; kk++) {
        float h = hd[i][3 * q + kk];
        s0 += h * wsr[i * 3 + kk]; s1 += h * wsr[192 + i * 3 + kk];
        u0 += h * wsr[12288 + i * 3 + kk]; u1 += h * wsr[12288 + 192 + i * 3 + kk];
      }
    int o = 2 * oq;
    g2s[o][q] = sigm(s0 + p2b[o]) * tanhf(u0 + p2b[o + 64]);
    g2s[o + 1][q] = sigm(s1 + p2b[o + 1]) * tanhf(u1 + p2b[o + 65]);
  } else if (tid < 192) {
    int r = tid - 128;
    int oq = r / 2, q = r & 1;
    float s0 = 0, s1 = 0, u0 = 0, u1 = 0;
    const float* wsr = p3w + (2 * oq) * 384;
    for (int i = 0; i < 64; i++)
#pragma unroll
      for (int kk = 0; kk < 6; kk++) {
        float h = hd[i][6 * q + kk];
        s0 += h * wsr[i * 6 + kk]; s1 += h * wsr[384 + i * 6 + kk];
        u0 += h * wsr[24576 + i * 6 + kk]; u1 += h * wsr[24576 + 384 + i * 6 + kk];
      }
    int o = 2 * oq;
    g3s[o][q] = sigm(s0 + p3b[o]) * tanhf(u0 + p3b[o + 64]);
    g3s[o + 1][q] = sigm(s1 + p3b[o + 1]) * tanhf(u1 + p3b[o + 65]);
  }
  __syncthreads();
  if (tid < 192) {
    int oq = tid / 12, t = tid - 12 * (tid / 12);
    float a0 = 0, a1 = 0, a2 = 0, a3 = 0;
    const float* w0 = pcw + (4 * oq) * 192;
    for (int c = 0; c < 64; c++) {
      float v = g1s[c][t];
      a0 += v * w0[c]; a1 += v * w0[192 + c];
      a2 += v * w0[384 + c]; a3 += v * w0[576 + c];
    }
    float c4 = fminf(fmaxf((t - 1) * (1.f / 3.f), 0.f), 3.f);
    int q0 = (int)c4;
    float f4 = c4 - (float)q0;
    int q1 = min(q0 + 1, 3);
    for (int c = 0; c < 64; c++) {
      float v = (1.f - f4) * g2s[c][q0] + f4 * g2s[c][q1];
      a0 += v * w0[64 + c]; a1 += v * w0[192 + 64 + c];
      a2 += v * w0[384 + 64 + c]; a3 += v * w0[576 + 64 + c];
    }
    float f2 = fminf(fmaxf((2 * t - 5) * (1.f / 12.f), 0.f), 1.f);
    for (int c = 0; c < 64; c++) {
      float v = (1.f - f2) * g3s[c][0] + f2 * g3s[c][1];
      a0 += v * w0[128 + c]; a1 += v * w0[192 + 128 + c];
      a2 += v * w0[384 + 128 + c]; a3 += v * w0[576 + 128 + c];
    }
    float av[4] = {a0, a1, a2, a3};
#pragma unroll
    for (int k = 0; k < 4; k++) {
      int o = 4 * oq + k;
      float y = av[k] + pcb[o];
      float s1 = pbg[o] / sqrtf(pbv[o] + 1e-5f);
      float fv = (y - pbm[o]) * s1 + pbb[o];
      fu[o][t] = fv;
      float s2 = bng[o] / sqrtf(bnv[o] + 1e-5f);
      xr[o][t] = (fv + xr[o][t] - bnm[o]) * s2 + bnb[o];
    }
  }
  __syncthreads();
  if (tid < 192) {
    int c = tid / 3, ch = tid - 3 * (tid / 3);
    *(float4*)(x + base + (size_t)c * NT + ch * 4) = *(float4*)&xr[c][ch * 4];
  }
  if (tid < 128) {
    float a = skb[tid];
    const float* wr = skw + tid * 64;
    for (int c = 0; c < 64; c++) a += fu[c][11] * wr[c];
    size_t o = ((size_t)b * 128 + tid) * N_ + n;
    skipb[o] = accum ? (skipb[o] + a) : a;
  }
}

// ---------------- k6: end MLP per (b,n) — fp32 output ----------------
__global__ __launch_bounds__(256) void k6_end(const float* __restrict__ skip,
                                              const float* __restrict__ w1,
                                              const float* __restrict__ b1,
                                              const float* __restrict__ w2,
                                              const float* __restrict__ b2,
                                              float* __restrict__ out) {
  __shared__ float sk[128];
  __shared__ float h[256];
  const int blk = blockIdx.x;
  const int b = blk / N_;
  const int n = blk - N_ * b;
  const int tid = threadIdx.x;
  if (tid < 128) sk[tid] = fmaxf(skip[((size_t)b * 128 + tid) * N_ + n], 0.f);
  __syncthreads();
  {
    float a = b1[tid];
    for (int s = 0; s < 128; s++) a += w1[tid * 128 + s] * sk[s];
    h[tid] = fmaxf(a, 0.f);
  }
  __syncthreads();
  if (tid < 12) {
    float a = b2[tid];
    for (int e = 0; e < 256; e++) a += w2[tid * 256 + e] * h[e];
    out[((size_t)b * 12 + tid) * N_ + n] = a;
  }
}

// ---------------- host ----------------
extern "C" void kernel_launch(void* const* d_in, const int* in_sizes, int n_in,
                              void* d_out, int out_size, void* d_ws, size_t ws_size,
                              hipStream_t stream) {
  (void)in_sizes; (void)n_in;
  if (ws_size < (size_t)44 * 1024 * 1024) {
    k_sentinel<<<(out_size + 255) / 256, 256, 0, stream>>>((float*)d_out, out_size);
    return;
  }
  const float* src = (const float*)d_in[0];
  const int* TE = (const int*)d_in[1];
  const float* sp = (const float*)d_in[2];
  const float* tp = (const float*)d_in[3];
  const float* SE = (const float*)d_in[4];
  const float* tmlp1_w = (const float*)d_in[5];
  const float* tmlp1_b = (const float*)d_in[6];
  const float* tmlp2_w = (const float*)d_in[7];
  const float* tmlp2_b = (const float*)d_in[8];
  const float* smlp1_w = (const float*)d_in[9];
  const float* smlp1_b = (const float*)d_in[10];
  const float* smlp2_w = (const float*)d_in[11];
  const float* smlp2_b = (const float*)d_in[12];
  const float* start_w = (const float*)d_in[13];
  const float* start_b = (const float*)d_in[14];
  const float* th1w = (const float*)d_in[15];
  const float* th1b = (const float*)d_in[16];
  const float* th2w = (const float*)d_in[17];
  const float* th2b = (const float*)d_in[18];
  const float* stw = (const float*)d_in[19];
  const float* stb = (const float*)d_in[20];
  const float* stg = (const float*)d_in[21];
  const float* stbb = (const float*)d_in[22];
  const float* stm = (const float*)d_in[23];
  const float* stv = (const float*)d_in[24];
  const float* p1w = (const float*)d_in[25];
  const float* p1b = (const float*)d_in[26];
  const float* p2w = (const float*)d_in[27];
  const float* p2b = (const float*)d_in[28];
  const float* p3w = (const float*)d_in[29];
  const float* p3b = (const float*)d_in[30];
  const float* pcw = (const float*)d_in[31];
  const float* pcb = (const float*)d_in[32];
  const float* pbg = (const float*)d_in[33];
  const float* pbb = (const float*)d_in[34];
  const float* pbm = (const float*)d_in[35];
  const float* pbv = (const float*)d_in[36];
  const float* skw = (const float*)d_in[37];
  const float* skb = (const float*)d_in[38];
  const float* bng = (const float*)d_in[39];
  const float* bnb = (const float*)d_in[40];
  const float* bnm = (const float*)d_in[41];
  const float* bnv = (const float*)d_in[42];
  const float* e1w = (const float*)d_in[43];
  const float* e1b = (const float*)d_in[44];
  const float* e2w = (const float*)d_in[45];
  const float* e2b = (const float*)d_in[46];

  float* ws = (float*)d_ws;
  float* coef = ws + 0;              // 2*8*66
  float* LsT  = ws + 8192;           // 325*328
  float* x    = ws + 4194304;        // [B,64,N,T]
  float* xst  = ws + 6291456;        // x_st
  float* skipb= ws + 10485760;       // [B,128,N]

  k0_convert<<<(N_ * LSP + 255) / 256, 256, 0, stream>>>(sp, LsT);
  k1_embed<<<1, 256, 0, stream>>>(TE, SE, tmlp1_w, tmlp1_b, tmlp2_w, tmlp2_b,
                                  smlp1_w, smlp1_b, smlp2_w, smlp2_b,
                                  th1w, th1b, th2w, th2b, coef);
  k2_start<<<(B_ * C_ * NT + 255) / 256, 256, 0, stream>>>(src, start_w, start_b, x);

  for (int l = 0; l < 2; l++) {
    k3_basis<<<512, 512, 0, stream>>>(x, LsT, tp, coef + l * 528, xst);
    k45_layer<<<B_ * N_, 256, 0, stream>>>(
        x, xst,
        stw + l * 8192, stb + l * 64, stg + l * 64, stbb + l * 64,
        stm + l * 64, stv + l * 64,
        p1w + l * 8192, p1b + l * 128,
        p2w + l * 24576, p2b + l * 128,
        p3w + l * 49152, p3b + l * 128,
        pcw + l * 12288, pcb + l * 64,
        pbg + l * 64, pbb + l * 64, pbm + l * 64, pbv + l * 64,
        bng + l * 64, bnb + l * 64, bnm + l * 64, bnv + l * 64,
        skw + l * 8192, skb + l * 128,
        skipb, l);
  }
  k6_end<<<B_ * N_, 256, 0, stream>>>(skipb, e1w, e1b, e2w, e2b, (float*)d_out);
}